// Round 4
// baseline (1778.664 us; speedup 1.0000x reference)
//
#include <hip/hip_runtime.h>
#include <math.h>

// Problem constants
#define B_    8
#define S_    4096
#define T_    77
#define C_    1280
#define CENC_ 2048
#define H_    20
#define D_    64
#define HD_   1280
#define M1_   (B_*S_)     // 32768 rows for Q / O GEMMs
#define MKV_  (B_*T_)     // 616 rows for K/V GEMM
#define KTOK_ 12          // ceil(77*0.15)
#define KPOS_ 1229        // ceil(4096*0.3)
#define SCALE_ 0.125f     // 1/sqrt(64)
#define CMIX_  0.15f      // STRENGTH*(1-ALPHA)
#define CINJ_  (0.25f/7.0f) // FIW*STRENGTH/(B-1)
#define SEGT_  20         // K-tiles (of 64) per 1280-wide segment

typedef __attribute__((ext_vector_type(8))) short bf16x8;
typedef __attribute__((ext_vector_type(4))) float f32x4;

#define AS_G __attribute__((address_space(1)))
#define AS_L __attribute__((address_space(3)))
#define MFMA16 __builtin_amdgcn_mfma_f32_16x16x32_bf16
#define SBAR() asm volatile("s_barrier" ::: "memory")
#define VM8 asm volatile("s_waitcnt vmcnt(8)" ::: "memory")
#define VM0 asm volatile("s_waitcnt vmcnt(0)" ::: "memory")
#define NOP ((void)0)

// ---------------------------------------------------------------------------
// bf16 helpers (RNE)
// ---------------------------------------------------------------------------
__device__ inline unsigned short f2bf(float x)
{
    union { float f; unsigned u; } v; v.f = x;
    const unsigned r = v.u + 0x7FFFu + ((v.u >> 16) & 1u);
    return (unsigned short)(r >> 16);
}
__device__ inline float bf2f(unsigned short h)
{
    union { float f; unsigned u; } v; v.u = ((unsigned)h) << 16;
    return v.f;
}

// split 8 consecutive fp32 -> bf16 hi + lo fragments (two aligned float4s)
__device__ inline void split_frag(const float* __restrict__ p, bf16x8& hi, bf16x8& lo)
{
    const float4 a = *(const float4*)p;
    const float4 b = *(const float4*)(p + 4);
    float f[8] = {a.x, a.y, a.z, a.w, b.x, b.y, b.z, b.w};
    #pragma unroll
    for (int e = 0; e < 8; ++e) {
        const unsigned short h = f2bf(f[e]);
        hi[e] = (short)h;
        lo[e] = (short)f2bf(f[e] - bf2f(h));
    }
}

// ---------------------------------------------------------------------------
// Split fp32 -> bf16 hi + bf16 lo (residual). One float4 per thread.
// ---------------------------------------------------------------------------
__global__ __launch_bounds__(256)
void split_convert_kernel(const float* __restrict__ x, unsigned short* __restrict__ hi,
                          unsigned short* __restrict__ lo)
{
    const size_t i4 = (size_t)blockIdx.x * 256 + threadIdx.x;
    const float4 v = ((const float4*)x)[i4];
    ushort4 h, l;
    h.x = f2bf(v.x); l.x = f2bf(v.x - bf2f(h.x));
    h.y = f2bf(v.y); l.y = f2bf(v.y - bf2f(h.y));
    h.z = f2bf(v.z); l.z = f2bf(v.z - bf2f(h.z));
    h.w = f2bf(v.w); l.w = f2bf(v.w - bf2f(h.w));
    ((ushort4*)hi)[i4] = h;
    ((ushort4*)lo)[i4] = l;
}

// ---------------------------------------------------------------------------
// Weight transpose + split: W[K=1280][N=1280] fp32 -> Thi/Tlo [N][K] bf16.
// ---------------------------------------------------------------------------
__global__ __launch_bounds__(256)
void wsplitT_kernel(const float* __restrict__ W, unsigned short* __restrict__ Thi,
                    unsigned short* __restrict__ Tlo)
{
    __shared__ float tile[32][33];
    const int tx = threadIdx.x & 31, ty = threadIdx.x >> 5;
    const int n0 = blockIdx.x * 32, k0 = blockIdx.y * 32;
    #pragma unroll
    for (int i = 0; i < 4; ++i) {
        const int kk = ty + i * 8;
        tile[kk][tx] = W[(size_t)(k0 + kk) * 1280 + n0 + tx];
    }
    __syncthreads();
    #pragma unroll
    for (int i = 0; i < 4; ++i) {
        const int nn = ty + i * 8;
        const float v = tile[tx][nn];               // = W[k0+tx][n0+nn]
        const unsigned short h = f2bf(v);
        const size_t oi = (size_t)(n0 + nn) * 1280 + k0 + tx;
        Thi[oi] = h;
        Tlo[oi] = f2bf(v - bf2f(h));
    }
}

// ---------------------------------------------------------------------------
// Injection + fp32->bf16 for the O-projection A operand:
// a = ctx*(1-8*cf) + cf*csum, cf = posm[row]*CINJ_.
// ---------------------------------------------------------------------------
__global__ __launch_bounds__(256)
void inject_convert_kernel(const float* __restrict__ ctx, const float* __restrict__ csum,
                           const float* __restrict__ posm, unsigned short* __restrict__ outb)
{
    const size_t i4 = (size_t)blockIdx.x * 256 + threadIdx.x;   // float4 index
    const int row = (int)(i4 / 320);
    const int c4  = (int)(i4 % 320);
    const float cf = posm[row] * CINJ_;
    const float am = 1.0f - 8.0f * cf;
    const float4 c  = ((const float4*)ctx)[i4];
    const float4 cs = ((const float4*)csum)[(size_t)(row & (S_ - 1)) * 320 + c4];
    ushort4 h;
    h.x = f2bf(c.x * am + cf * cs.x);
    h.y = f2bf(c.y * am + cf * cs.y);
    h.z = f2bf(c.z * am + cf * cs.z);
    h.w = f2bf(c.w * am + cf * cs.w);
    ((ushort4*)outb)[i4] = h;
}

// ---------------------------------------------------------------------------
// 8-phase 256x256 MFMA GEMM (T3+T4+T5), r3.
// C[M x 1280] = sum over 3 segments of Aseg[M x 1280] * Bseg^T[1280 x 1280]
// (segment concat realizes the split-bf16 3-product sum for Q-proj; O-proj
// passes the same pointers 3x with NTILES=20 so only seg 0 is used).
//
// Geometry: BM=BN=256, BK=64, 8 waves (2M x 4N) of 512 thr; per-wave output
// 128x64 = acc[8][4] f32x4. LDS 128KB: sA/sB [2 buf][8 kc][256 rows][16B],
// k-chunk-major -> a quad's 16 lanes read 16 consecutive 16B chunks = 256B,
// all 32 banks, conflict-free by construction (no swizzle needed).
// global_load_lds dest is wave-linear; per-lane GLOBAL source is permuted.
//
// Schedule (iter i computes tiles t0=2i->buf0, t1=2i+1->buf1; 8 phases):
//   ph1: rd buf0 ks0 mlo +B | stage A_ks1(t1)->buf1   (region last read i-1:ph7-8)
//   ph2: rd buf0 ks0 mhi    | stage B_ks1(t1)->buf1 | vmcnt(8)
//   ph3: rd buf0 ks1 mlo +B | stage A_ks0(t0+2)->buf0 (last read ph1-2)
//   ph4: rd buf0 ks1 mhi    | stage B_ks0(t0+2)->buf0 | vmcnt(8)
//   ph5: rd buf1 ks0 mlo +B | stage A_ks1(t0+2)->buf0 (last read ph3-4)
//   ph6: rd buf1 ks0 mhi    | stage B_ks1(t0+2)->buf0 | vmcnt(8)
//   ph7: rd buf1 ks1 mlo +B | stage A_ks0(t1+2)->buf1 (last read ph5-6)
//   ph8: rd buf1 ks1 mhi    | stage B_ks0(t1+2)->buf1 | vmcnt(8)
// Every unit is consumed 5-6 phases after issue; vmcnt(8) = "4 newest units
// may be outstanding" -> oldest have LANDED (FIFO vmcnt semantics, m135)
// before the barrier preceding their first read. Stage targets are regions
// whose last ds_read completed before the previous trailing barrier.
// Prologue: 6 units + vmcnt(8) (=> oldest 2 units landed) + barrier.
// Last iteration peeled: ph1-2 stage t1's ks1 then vmcnt(0) drain; ph3-8
// pure compute (closes the tail-underflow race of counted vmcnt).
// ---------------------------------------------------------------------------
#define PHASE(BUF, KS, MH, RB, STG, VM)                                         \
    {                                                                           \
        const unsigned short* SAp = sA[BUF];                                    \
        _Pragma("unroll")                                                       \
        for (int j = 0; j < 4; ++j)                                             \
            aF[j] = *(const bf16x8*)(SAp + ((((KS)*4+quad)*256) + wr*128 + (MH)*64 + j*16 + lrow)*8); \
        if (RB) {                                                               \
            const unsigned short* SBp = sB[BUF];                                \
            _Pragma("unroll")                                                   \
            for (int g = 0; g < 4; ++g)                                         \
                bF[g] = *(const bf16x8*)(SBp + ((((KS)*4+quad)*256) + wc*64 + g*16 + lrow)*8); \
        }                                                                       \
        STG;                                                                    \
        SBAR();                                                                 \
        asm volatile("s_waitcnt lgkmcnt(0)" ::: "memory");                      \
        __builtin_amdgcn_sched_barrier(0);                                      \
        __builtin_amdgcn_s_setprio(1);                                          \
        _Pragma("unroll")                                                       \
        for (int j = 0; j < 4; ++j)                                             \
            _Pragma("unroll")                                                   \
            for (int g = 0; g < 4; ++g)                                         \
                acc[(MH)*4+j][g] = MFMA16(aF[j], bF[g], acc[(MH)*4+j][g], 0, 0, 0); \
        __builtin_amdgcn_s_setprio(0);                                          \
        VM;                                                                     \
        SBAR();                                                                 \
    }

template<bool FUSE>
__global__ __launch_bounds__(512, 2)
void gemm8p_kernel(const unsigned short* __restrict__ A0, const unsigned short* __restrict__ A1,
                   const unsigned short* __restrict__ A2,
                   const unsigned short* __restrict__ B0, const unsigned short* __restrict__ B1,
                   const unsigned short* __restrict__ B2,
                   float* __restrict__ Cout, int NTILES,
                   const float* __restrict__ bias, const float* __restrict__ resid)
{
    __shared__ unsigned short sA[2][16384];   // [buf][kc(8)][row(256)][8 bf16]
    __shared__ unsigned short sB[2][16384];

    const int tid  = threadIdx.x;
    const int lane = tid & 63;
    const int wid  = tid >> 6;
    const int quad = lane >> 4;
    const int lrow = lane & 15;
    const int wr = wid >> 2;          // 0..1  (m half of the 256 tile)
    const int wc = wid & 3;           // 0..3  (n quarter)

    // bijective XCD swizzle (grid % 8 == 0), then n-panel-major decomposition
    const int nwg = gridDim.x;
    const int cpx = nwg >> 3;
    int sw = ((int)blockIdx.x & 7) * cpx + ((int)blockIdx.x >> 3);
    const int m0 = (sw & 127) * 256;          // 128 m-tiles
    const int n0 = (sw >> 7) * 256;           // 5 n-tiles

    // per-thread staging offsets: chunk c = tid + j*512 -> (kcl = c>>8, row = c&255)
    int voff[2], cdst[2];
    #pragma unroll
    for (int j = 0; j < 2; ++j) {
        const int c = tid + j * 512;
        voff[j] = (c & 255) * 1280 + (c >> 8) * 8;   // global: row*ldk + kcl*8
        cdst[j] = c * 8;                             // LDS ushort offset in region
    }

    auto stageA = [&](int t, int ks) {
        const int seg = t / SEGT_;
        const int kt  = t - seg * SEGT_;
        const unsigned short* Ab = (seg == 0) ? A0 : (seg == 1) ? A1 : A2;
        const size_t base = (size_t)m0 * 1280 + kt * 64 + ks * 32;
        unsigned short* reg = &sA[t & 1][ks * 8192];
        #pragma unroll
        for (int j = 0; j < 2; ++j)
            __builtin_amdgcn_global_load_lds((const AS_G void*)(Ab + base + voff[j]),
                                             (AS_L void*)(reg + cdst[j]), 16, 0, 0);
    };
    auto stageB = [&](int t, int ks) {
        const int seg = t / SEGT_;
        const int kt  = t - seg * SEGT_;
        const unsigned short* Bb = (seg == 0) ? B0 : (seg == 1) ? B1 : B2;
        const size_t base = (size_t)n0 * 1280 + kt * 64 + ks * 32;
        unsigned short* reg = &sB[t & 1][ks * 8192];
        #pragma unroll
        for (int j = 0; j < 2; ++j)
            __builtin_amdgcn_global_load_lds((const AS_G void*)(Bb + base + voff[j]),
                                             (AS_L void*)(reg + cdst[j]), 16, 0, 0);
    };

    f32x4 acc[8][4] = {};
    bf16x8 aF[4], bF[4];

    const int NI = NTILES >> 1;               // iterations (2 tiles each); NI >= 2

    // prologue: tile0 all 4 units + tile1 ks0 units, then allow 4 newest units
    stageA(0, 0); stageB(0, 0); stageA(0, 1); stageB(0, 1); stageA(1, 0); stageB(1, 0);
    VM8;        // 6 units outstanding-cap 8 loads => oldest 2 units (tile0 ks0) landed
    SBAR();

    for (int it = 0; it < NI - 1; ++it) {
        const int t0 = 2 * it, t1 = 2 * it + 1;
        PHASE(0, 0, 0, true,  stageA(t1, 1),     NOP);
        PHASE(0, 0, 1, false, stageB(t1, 1),     VM8);
        PHASE(0, 1, 0, true,  stageA(t0 + 2, 0), NOP);
        PHASE(0, 1, 1, false, stageB(t0 + 2, 0), VM8);
        PHASE(1, 0, 0, true,  stageA(t0 + 2, 1), NOP);
        PHASE(1, 0, 1, false, stageB(t0 + 2, 1), VM8);
        PHASE(1, 1, 0, true,  stageA(t1 + 2, 0), NOP);
        PHASE(1, 1, 1, false, stageB(t1 + 2, 0), VM8);
    }
    {   // peeled last iteration: only t1's ks1 still to stage, then drain
        const int t1 = NTILES - 1;
        PHASE(0, 0, 0, true,  stageA(t1, 1), NOP);
        PHASE(0, 0, 1, false, stageB(t1, 1), VM0);
        PHASE(0, 1, 0, true,  NOP, NOP);
        PHASE(0, 1, 1, false, NOP, NOP);
        PHASE(1, 0, 0, true,  NOP, NOP);
        PHASE(1, 0, 1, false, NOP, NOP);
        PHASE(1, 1, 0, true,  NOP, NOP);
        PHASE(1, 1, 1, false, NOP, NOP);
    }

    // Epilogue: C/D layout col = lane&15, row = quad*4 + reg (m89/m91-verified)
    #pragma unroll
    for (int f = 0; f < 8; ++f) {
        #pragma unroll
        for (int g = 0; g < 4; ++g) {
            const int col = n0 + wc * 64 + g * 16 + lrow;
            #pragma unroll
            for (int r2 = 0; r2 < 4; ++r2) {
                const int row = m0 + wr * 128 + f * 16 + quad * 4 + r2;
                float v = acc[f][g][r2];
                if constexpr (FUSE)
                    v += bias[col] + resid[(size_t)row * 1280 + col];
                Cout[(size_t)row * 1280 + col] = v;
            }
        }
    }
}

// ---------------------------------------------------------------------------
// fp32 GEMM, 64x64 tile, BK=16, 256 threads, 4x4 micro-tile. For K/V
// projections (M=616, K=2048, N=1280) — stays fp32 (feeds scoring path).
// ---------------------------------------------------------------------------
__global__ __launch_bounds__(256)
void gemm64_kernel(const float* __restrict__ A,
                   const float* __restrict__ B0, const float* __restrict__ B1,
                   float* __restrict__ C0, float* __restrict__ C1,
                   int M, int N, int K)
{
    const float* Bm = blockIdx.z ? B1 : B0;
    float* Cout = blockIdx.z ? C1 : C0;
    __shared__ float As[16][64];
    __shared__ float Bs[16][64];
    const int tid = threadIdx.x;
    const int n0 = blockIdx.x * 64;
    const int m0 = blockIdx.y * 64;
    const int tx = tid & 15, ty = tid >> 4;
    const int ar = tid >> 2;
    const int ak = (tid & 3) << 2;
    const int bk = tid >> 4;
    const int bn = (tid & 15) << 2;

    float acc[4][4] = {};
    const int arow = m0 + ar;
    const bool avalid = arow < M;
    const float* Ap = A + (size_t)arow * K + ak;
    const float* Bp = Bm + (size_t)bk * N + n0 + bn;

    for (int k0 = 0; k0 < K; k0 += 16) {
        const float4 a = avalid ? *(const float4*)(Ap + k0) : make_float4(0.f,0.f,0.f,0.f);
        const float4 b = *(const float4*)(Bp + (size_t)k0 * N);
        __syncthreads();
        As[ak+0][ar] = a.x; As[ak+1][ar] = a.y; As[ak+2][ar] = a.z; As[ak+3][ar] = a.w;
        *(float4*)&Bs[bk][bn] = b;
        __syncthreads();
        #pragma unroll
        for (int kk = 0; kk < 16; ++kk) {
            const float4 av = *(const float4*)&As[kk][ty*4];
            const float4 bv = *(const float4*)&Bs[kk][tx*4];
            const float arr[4] = {av.x, av.y, av.z, av.w};
            const float brr[4] = {bv.x, bv.y, bv.z, bv.w};
            #pragma unroll
            for (int r = 0; r < 4; ++r)
                #pragma unroll
                for (int c = 0; c < 4; ++c)
                    acc[r][c] = fmaf(arr[r], brr[c], acc[r][c]);
        }
    }
    #pragma unroll
    for (int r = 0; r < 4; ++r) {
        const int row = m0 + ty * 4 + r;
        if (row < M) {
            const float4 cv = make_float4(acc[r][0], acc[r][1], acc[r][2], acc[r][3]);
            *(float4*)(Cout + (size_t)row * N + n0 + tx * 4) = cv;
        }
    }
}

__device__ inline bool first_pair(float va, int ia, float vb, int ib)
{
    return (va > vb) || (va == vb && ia < ib);
}

// descending by (value, then index asc) — matches lax.top_k tie-break
__device__ inline void bitonic_desc(float* vals, int* idxs, int n, int tid, int nt)
{
    for (int k = 2; k <= n; k <<= 1) {
        for (int j = k >> 1; j > 0; j >>= 1) {
            __syncthreads();
            for (int i = tid; i < n; i += nt) {
                const int l = i ^ j;
                if (l > i) {
                    const float vi = vals[i], vl = vals[l];
                    const int   ii = idxs[i], il = idxs[l];
                    const bool up = (i & k) == 0;
                    const bool sw = up ? first_pair(vl, il, vi, ii)
                                       : first_pair(vi, ii, vl, il);
                    if (sw) { vals[i] = vl; vals[l] = vi; idxs[i] = il; idxs[l] = ii; }
                }
            }
        }
    }
    __syncthreads();
}

// ---------------------------------------------------------------------------
// Pass A (MFMA): swapped QK^T -> per-lane logits for 16 s-cols (s = lane&15),
// t = nt*16 + quad*4 + r. 4-product split bf16 QK (fp32-level accuracy; the
// logits feed the top-k masks, which must not flip). Softmax over t = register
// max/sum + shfl_xor(16/32) quad reduce. Accumulate sum_s p per t -> tokp.
// Grid: 2560 blocks = b(8) x h(20) x s-chunk(16); 4 waves x 4 s-tiles = 256 s.
// ---------------------------------------------------------------------------
__global__ __launch_bounds__(256)
void pass_a_kernel(const float* __restrict__ q, const float* __restrict__ kbuf,
                   float* __restrict__ tokp)
{
    __shared__ unsigned short khi[80 * 64];   // [t][d] bf16, XOR-swizzled rows
    __shared__ unsigned short klo[80 * 64];
    __shared__ float wsum[4][80];
    const int g = blockIdx.x;
    const int b = g / 320;
    const int rem = g % 320;
    const int h = rem >> 4;
    const int chunk = rem & 15;
    const int tid = threadIdx.x;

    // stage K slice -> swizzled bf16 hi/lo (T2 swizzle: byte ^= (t&7)<<4)
    for (int i = tid; i < 80 * 16; i += 256) {
        const int t = i >> 4, j = i & 15;                 // d0 = 4*j
        float4 v = make_float4(0.f, 0.f, 0.f, 0.f);
        if (t < T_) v = *(const float4*)(kbuf + (size_t)(b * T_ + t) * HD_ + h * D_ + 4 * j);
        ushort4 hh, ll;
        hh.x = f2bf(v.x); ll.x = f2bf(v.x - bf2f(hh.x));
        hh.y = f2bf(v.y); ll.y = f2bf(v.y - bf2f(hh.y));
        hh.z = f2bf(v.z); ll.z = f2bf(v.z - bf2f(hh.z));
        hh.w = f2bf(v.w); ll.w = f2bf(v.w - bf2f(hh.w));
        const int byt = t * 128 + ((8 * j) ^ ((t & 7) << 4));
        *(ushort4*)((char*)khi + byt) = hh;
        *(ushort4*)((char*)klo + byt) = ll;
    }
    __syncthreads();

    const int wid = tid >> 6, lane = tid & 63;
    const int lrow = lane & 15, quad = lane >> 4;

    f32x4 tokacc[5] = {};
    for (int st = 0; st < 4; ++st) {
        const int s = chunk * 256 + wid * 64 + st * 16 + lrow;
        const float* qp = q + (size_t)(b * S_ + s) * HD_ + h * D_;
        bf16x8 qhi[2], qlo[2];
        #pragma unroll
        for (int ks = 0; ks < 2; ++ks)
            split_frag(qp + ks * 32 + quad * 8, qhi[ks], qlo[ks]);

        f32x4 acc[5] = {};
        #pragma unroll
        for (int nt = 0; nt < 5; ++nt) {
            #pragma unroll
            for (int ks = 0; ks < 2; ++ks) {
                const int krow = nt * 16 + lrow;
                const int byt = krow * 128 + ((64 * ks + 16 * quad) ^ ((krow & 7) << 4));
                const bf16x8 kh = *(const bf16x8*)((const char*)khi + byt);
                const bf16x8 kl = *(const bf16x8*)((const char*)klo + byt);
                acc[nt] = MFMA16(kh, qhi[ks], acc[nt], 0, 0, 0);
                acc[nt] = MFMA16(kh, qlo[ks], acc[nt], 0, 0, 0);
                acc[nt] = MFMA16(kl, qhi[ks], acc[nt], 0, 0, 0);
                acc[nt] = MFMA16(kl, qlo[ks], acc[nt], 0, 0, 0);
            }
        }
        float m = -1e30f;
        #pragma unroll
        for (int nt = 0; nt < 5; ++nt)
            #pragma unroll
            for (int r = 0; r < 4; ++r) {
                const int t = nt * 16 + quad * 4 + r;
                const float l = (t < T_) ? acc[nt][r] * SCALE_ : -1e30f;
                acc[nt][r] = l;
                m = fmaxf(m, l);
            }
        m = fmaxf(m, __shfl_xor(m, 16, 64));
        m = fmaxf(m, __shfl_xor(m, 32, 64));
        float Lp = 0.f;
        #pragma unroll
        for (int nt = 0; nt < 5; ++nt)
            #pragma unroll
            for (int r = 0; r < 4; ++r) {
                const float e = __expf(acc[nt][r] - m);
                acc[nt][r] = e;
                Lp += e;
            }
        float L = Lp + __shfl_xor(Lp, 16, 64);
        L += __shfl_xor(L, 32, 64);
        const float invL = 1.0f / L;
        #pragma unroll
        for (int nt = 0; nt < 5; ++nt)
            #pragma unroll
            for (int r = 0; r < 4; ++r)
                tokacc[nt][r] = fmaf(acc[nt][r], invL, tokacc[nt][r]);
    }
    // reduce over the 16 s-columns (lane bits 0..3), write per-wave partials
    #pragma unroll
    for (int nt = 0; nt < 5; ++nt)
        #pragma unroll
        for (int r = 0; r < 4; ++r) {
            float v = tokacc[nt][r];
            v += __shfl_xor(v, 1, 64);
            v += __shfl_xor(v, 2, 64);
            v += __shfl_xor(v, 4, 64);
            v += __shfl_xor(v, 8, 64);
            if (lrow == 0) wsum[wid][nt * 16 + quad * 4 + r] = v;
        }
    __syncthreads();
    for (int t = tid; t < T_; t += 256)
        tokp[(size_t)g * T_ + t] = (wsum[0][t] + wsum[1][t]) + (wsum[2][t] + wsum[3][t]);
}

// ---------------------------------------------------------------------------
// Top-k over 77 token scores per batch -> tok_mask. 8 blocks x 128 threads.
// ---------------------------------------------------------------------------
__global__ __launch_bounds__(128)
void topk_tok_kernel(const float* __restrict__ tokp, float* __restrict__ tokm)
{
    __shared__ float vals[128];
    __shared__ int idxs[128];
    const int b = blockIdx.x, tid = threadIdx.x;
    float v = -1e30f;
    if (tid < T_) {
        float sm = 0.f;
        for (int j = 0; j < 320; ++j) sm += tokp[(size_t)(b * 320 + j) * T_ + tid];
        v = sm;
    }
    vals[tid] = v; idxs[tid] = tid;
    bitonic_desc(vals, idxs, 128, tid, 128);
    if (tid < T_) tokm[b * T_ + tid] = 0.f;
    __syncthreads();
    if (tid < KTOK_) tokm[b * T_ + idxs[tid]] = 1.0f;
}

// ---------------------------------------------------------------------------
// K/V cross-frame mixing: kd = k2-k (delta, mask folded in), v2 = mixed v.
// ---------------------------------------------------------------------------
__global__ __launch_bounds__(256)
void mix_kernel(const float* __restrict__ kbuf, const float* __restrict__ vbuf,
                const float* __restrict__ tokm,
                float* __restrict__ kd, float* __restrict__ v2)
{
    const int i = blockIdx.x * 256 + threadIdx.x;   // < 77*1280 = 98560
    const int t = i / HD_;
    float ks = 0.f, vs = 0.f;
    #pragma unroll
    for (int b = 0; b < B_; ++b) {
        ks += kbuf[(size_t)b * T_ * HD_ + i];
        vs += vbuf[(size_t)b * T_ * HD_ + i];
    }
    #pragma unroll
    for (int b = 0; b < B_; ++b) {
        const size_t gi = (size_t)b * T_ * HD_ + i;
        const float msk = tokm[b * T_ + t];
        const float kx = kbuf[gi], vx = vbuf[gi];
        kd[gi] = CMIX_ * msk * ((ks - 8.f * kx) * (1.0f / 7.0f));
        v2[gi] = vx + CMIX_ * msk * ((vs - 8.f * vx) * (1.0f / 7.0f));
    }
}

// ---------------------------------------------------------------------------
// Fused pass B+C (MFMA): swapped QK^T gives per-lane l1 (split, 4 products)
// and l2 = l1 + q·kd (kd bf16-hi; mask folded into kd). Register softmax for
// both; posp = masked mass of softmax(l1); p2 = softmax(l2) -> LDS round-trip
// per 32-wide k-step (hi/lo) -> swapped PV mfma(V^T, P) -> ctx.
// ---------------------------------------------------------------------------
__global__ __launch_bounds__(256)
void pass_bc_kernel(const float* __restrict__ q, const float* __restrict__ kbuf,
                    const float* __restrict__ kd, const float* __restrict__ v2,
                    const float* __restrict__ tokm,
                    float* __restrict__ posp, float* __restrict__ ctx)
{
    __shared__ unsigned short khi[80 * 64];     // [t][d] XOR-swizzled
    __shared__ unsigned short klo[80 * 64];
    __shared__ unsigned short kdh[80 * 64];
    __shared__ unsigned short vThi[64 * 88];    // [d][t] rows padded to 88
    __shared__ unsigned short vTlo[64 * 88];
    __shared__ unsigned short vguard[128];      // zeroed guard for vT overreads
    __shared__ unsigned short Pbuf[4][2][16 * 40]; // per-wave [hi/lo][s][tloc]
    __shared__ float smaskf[80];

    const int g = blockIdx.x;
    const int b = g / 320;
    const int rem = g % 320;
    const int h = rem >> 4;
    const int chunk = rem & 15;
    const int tid = threadIdx.x;

    // ---- stage K (hi/lo) + Kd (hi), swizzled ----
    for (int i = tid; i < 80 * 16; i += 256) {
        const int t = i >> 4, j = i & 15;
        float4 vk = make_float4(0.f, 0.f, 0.f, 0.f);
        float4 vd = make_float4(0.f, 0.f, 0.f, 0.f);
        if (t < T_) {
            const size_t gi = (size_t)(b * T_ + t) * HD_ + h * D_ + 4 * j;
            vk = *(const float4*)(kbuf + gi);
            vd = *(const float4*)(kd + gi);
        }
        ushort4 hh, ll, dd;
        hh.x = f2bf(vk.x); ll.x = f2bf(vk.x - bf2f(hh.x)); dd.x = f2bf(vd.x);
        hh.y = f2bf(vk.y); ll.y = f2bf(vk.y - bf2f(hh.y)); dd.y = f2bf(vd.y);
        hh.z = f2bf(vk.z); ll.z = f2bf(vk.z - bf2f(hh.z)); dd.z = f2bf(vd.z);
        hh.w = f2bf(vk.w); ll.w = f2bf(vk.w - bf2f(hh.w)); dd.w = f2bf(vd.w);
        const int byt = t * 128 + ((8 * j) ^ ((t & 7) << 4));
        *(ushort4*)((char*)khi + byt) = hh;
        *(ushort4*)((char*)klo + byt) = ll;
        *(ushort4*)((char*)kdh + byt) = dd;
    }
    // ---- stage V^T (hi/lo): rows d (88 cols, zero-padded past t=76) ----
    for (int i = tid; i < 64 * 22; i += 256) {
        const int d = i / 22, jg = i - d * 22;           // cols t = 4*jg..+3
        float vv[4];
        #pragma unroll
        for (int r = 0; r < 4; ++r) {
            const int t = 4 * jg + r;
            vv[r] = (t < T_) ? v2[(size_t)(b * T_ + t) * HD_ + h * D_ + d] : 0.f;
        }
        ushort4 hh, ll;
        hh.x = f2bf(vv[0]); ll.x = f2bf(vv[0] - bf2f(hh.x));
        hh.y = f2bf(vv[1]); ll.y = f2bf(vv[1] - bf2f(hh.y));
        hh.z = f2bf(vv[2]); ll.z = f2bf(vv[2] - bf2f(hh.z));
        hh.w = f2bf(vv[3]); ll.w = f2bf(vv[3] - bf2f(hh.w));
        const int byt = d * 176 + 8 * jg;
        *(ushort4*)((char*)vThi + byt) = hh;
        *(ushort4*)((char*)vTlo + byt) = ll;
    }
    for (int t = tid; t < 80; t += 256) smaskf[t] = (t < T_) ? tokm[b * T_ + t] : 0.f;
    for (int i = tid; i < 128; i += 256) vguard[i] = 0;
    __syncthreads();

    const int wid = tid >> 6, lane = tid & 63;
    const int lrow = lane & 15, quad = lane >> 4;
    unsigned short* Ph = &Pbuf[wid][0][0];
    unsigned short* Pl = &Pbuf[wid][1][0];

    // hoist per-lane token-mask values (constant across s-tiles)
    float smv[5][4];
    #pragma unroll
    for (int nt = 0; nt < 5; ++nt)
        #pragma unroll
        for (int r = 0; r < 4; ++r)
            smv[nt][r] = smaskf[nt * 16 + quad * 4 + r];

    for (int st = 0; st < 4; ++st) {
        const int s = chunk * 256 + wid * 64 + st * 16 + lrow;
        const float* qp = q + (size_t)(b * S_ + s) * HD_ + h * D_;
        bf16x8 qhi[2], qlo[2];
        #pragma unroll
        for (int ks = 0; ks < 2; ++ks)
            split_frag(qp + ks * 32 + quad * 8, qhi[ks], qlo[ks]);

        f32x4 acc1[5] = {}, accd[5] = {};
        #pragma unroll
        for (int nt = 0; nt < 5; ++nt) {
            #pragma unroll
            for (int ks = 0; ks < 2; ++ks) {
                const int krow = nt * 16 + lrow;
                const int byt = krow * 128 + ((64 * ks + 16 * quad) ^ ((krow & 7) << 4));
                const bf16x8 kh = *(const bf16x8*)((const char*)khi + byt);
                const bf16x8 kl = *(const bf16x8*)((const char*)klo + byt);
                const bf16x8 kdv = *(const bf16x8*)((const char*)kdh + byt);
                acc1[nt] = MFMA16(kh, qhi[ks], acc1[nt], 0, 0, 0);
                acc1[nt] = MFMA16(kh, qlo[ks], acc1[nt], 0, 0, 0);
                acc1[nt] = MFMA16(kl, qhi[ks], acc1[nt], 0, 0, 0);
                acc1[nt] = MFMA16(kl, qlo[ks], acc1[nt], 0, 0, 0);
                accd[nt] = MFMA16(kdv, qhi[ks], accd[nt], 0, 0, 0);
            }
        }

        // logits + dual softmax (l1: pos score; l2: second attention)
        float m1 = -1e30f, m2 = -1e30f;
        f32x4 l2v[5];
        #pragma unroll
        for (int nt = 0; nt < 5; ++nt)
            #pragma unroll
            for (int r = 0; r < 4; ++r) {
                const int t = nt * 16 + quad * 4 + r;
                const bool valid = t < T_;
                const float l1 = valid ? acc1[nt][r] * SCALE_ : -1e30f;
                const float l2 = valid ? l1 + accd[nt][r] * SCALE_ : -1e30f;
                acc1[nt][r] = l1;
                l2v[nt][r] = l2;
                m1 = fmaxf(m1, l1);
                m2 = fmaxf(m2, l2);
            }
        m1 = fmaxf(m1, __shfl_xor(m1, 16, 64));
        m1 = fmaxf(m1, __shfl_xor(m1, 32, 64));
        m2 = fmaxf(m2, __shfl_xor(m2, 16, 64));
        m2 = fmaxf(m2, __shfl_xor(m2, 32, 64));
        float L1p = 0.f, Smp = 0.f, L2p = 0.f;
        #pragma unroll
        for (int nt = 0; nt < 5; ++nt)
            #pragma unroll
            for (int r = 0; r < 4; ++r) {
                const float e1 = __expf(acc1[nt][r] - m1);
                L1p += e1;
                Smp = fmaf(e1, smv[nt][r], Smp);
                const float e2 = __expf(l2v[nt][r] - m2);
                l2v[nt][r] = e2;
                L2p += e2;
            }
        float L1 = L1p + __shfl_xor(L1p, 16, 64); L1 += __shfl_xor(L1, 32, 64);
        float Sm = Smp + __shfl_xor(Smp, 16, 64); Sm += __shfl_xor(Sm, 32, 64);
        float L2 = L2p + __shfl_xor(L2p, 16, 64); L2 += __shfl_xor(L2, 32, 64);
        if (quad == 0) posp[(size_t)(b * H_ + h) * S_ + s] = Sm / L1;
        const float invL2 = 1.0f / L2;
        #pragma unroll
        for (int nt = 0; nt < 5; ++nt)
            #pragma unroll
            for (int r = 0; r < 4; ++r)
                l2v[nt][r] *= invL2;

        // PV: per 32-wide k-step, P -> LDS (hi/lo) -> B-frags, V^T A-frags
        f32x4 pv[4] = {};
        #pragma unroll
        for (int ks = 0; ks < 3; ++ks) {
            asm volatile("s_waitcnt lgkmcnt(0)" ::: "memory");
            __builtin_amdgcn_sched_barrier(0);
            #pragma unroll
            for (int half = 0; half < 2; ++half) {
                const int nt = 2 * ks + half;
                ushort4 ph = {0, 0, 0, 0}, plw = {0, 0, 0, 0};
                if (nt < 5) {
                    ph.x = f2bf(l2v[nt][0]); plw.x = f2bf(l2v[nt][0] - bf2f(ph.x));
                    ph.y = f2bf(l2v[nt][1]); plw.y = f2bf(l2v[nt][1] - bf2f(ph.y));
                    ph.z = f2bf(l2v[nt][2]); plw.z = f2bf(l2v[nt][2] - bf2f(ph.z));
                    ph.w = f2bf(l2v[nt][3]); plw.w = f2bf(l2v[nt][3] - bf2f(ph.w));
                }
                const int pb = lrow * 80 + 32 * half + 8 * quad;
                *(ushort4*)((char*)Ph + pb) = ph;
                *(ushort4*)((char*)Pl + pb) = plw;
            }
            asm volatile("s_waitcnt lgkmcnt(0)" ::: "memory");
            __builtin_amdgcn_sched_barrier(0);
            const bf16x8 pH = *(const bf16x8*)((const char*)Ph + lrow * 80 + quad * 16);
            const bf16x8 pL = *(const bf16x8*)((const char*)Pl + lrow * 80 + quad * 16);
            #pragma unroll
            for (int mt = 0; mt < 4; ++mt) {
                const int vb = (mt * 16 + lrow) * 176 + 64 * ks + 16 * quad;
                const bf16x8 vH = *(const bf16x8*)((const char*)vThi + vb);
                const bf16x8 vL = *(const bf16x8*)((const char*)vTlo + vb);
                pv[mt] = MFMA16(vH, pH, pv[mt], 0, 0, 0);
                pv[mt] = MFMA16(vH, pL, pv[mt], 0, 0, 0);
                pv[mt] = MFMA16(vL, pH, pv[mt], 0, 0, 0);
            }
        }
        // ctx write: col = lane&15 = s, row(d) = mt*16 + quad*4 + reg
        float* cp = ctx + (size_t)(b * S_ + s) * HD_ + h * D_;
        #pragma unroll
        for (int mt = 0; mt < 4; ++mt) {
            const float4 o = make_float4(pv[mt][0], pv[mt][1], pv[mt][2], pv[mt][3]);
            *(float4*)(cp + mt * 16 + quad * 4) = o;
        }
    }
}

// ---------------------------------------------------------------------------
// Top-k over 4096 position scores per batch -> pos_mask. 8 blocks x 1024.
// ---------------------------------------------------------------------------
__global__ __launch_bounds__(1024)
void topk_pos_kernel(const float* __restrict__ posp, float* __restrict__ posm)
{
    __shared__ float vals[S_];
    __shared__ int idxs[S_];
    const int b = blockIdx.x, tid = threadIdx.x;
    for (int s = tid; s < S_; s += 1024) {
        float sm = 0.f;
        for (int h = 0; h < H_; ++h) sm += posp[(size_t)(b * H_ + h) * S_ + s];
        vals[s] = sm; idxs[s] = s;
    }
    bitonic_desc(vals, idxs, S_, tid, 1024);
    for (int s = tid; s < S_; s += 1024) posm[b * S_ + s] = 0.f;
    __syncthreads();
    for (int i = tid; i < KPOS_; i += 1024) posm[b * S_ + idxs[i]] = 1.0f;
}

// ---------------------------------------------------------------------------
// Batch-sum of context over b: csum[s,hd] = sum_b ctx[b,s,hd]. float4 lanes.
// ---------------------------------------------------------------------------
__global__ __launch_bounds__(256)
void ctxsum_kernel(const float* __restrict__ ctx, float* __restrict__ csum)
{
    const size_t i = (size_t)blockIdx.x * 256 + threadIdx.x;  // float4 index
    const float4* c = (const float4*)ctx;
    float4 a = c[i];
    #pragma unroll
    for (int b = 1; b < B_; ++b) {
        const float4 x = c[(size_t)b * (S_ * HD_ / 4) + i];
        a.x += x.x; a.y += x.y; a.z += x.z; a.w += x.w;
    }
    ((float4*)csum)[i] = a;
}

// ---------------------------------------------------------------------------
extern "C" void kernel_launch(void* const* d_in, const int* in_sizes, int n_in,
                              void* d_out, int out_size, void* d_ws, size_t ws_size,
                              hipStream_t stream)
{
    const float* hidden = (const float*)d_in[0];
    const float* enc    = (const float*)d_in[1];
    const float* Wq     = (const float*)d_in[2];
    const float* Wk     = (const float*)d_in[3];
    const float* Wv     = (const float*)d_in[4];
    const float* Wo     = (const float*)d_in[5];
    const float* bo     = (const float*)d_in[6];
    float* out = (float*)d_out;

    char* w = (char*)d_ws;
    float* q    = (float*)w; w += (size_t)M1_ * HD_ * 4;
    float* ctx  = (float*)w; w += (size_t)M1_ * HD_ * 4;
    float* kbuf = (float*)w; w += (size_t)B_ * T_ * HD_ * 4;
    float* vbuf = (float*)w; w += (size_t)B_ * T_ * HD_ * 4;
    float* kd   = (float*)w; w += (size_t)B_ * T_ * HD_ * 4;
    float* v2   = (float*)w; w += (size_t)B_ * T_ * HD_ * 4;
    float* csum = (float*)w; w += (size_t)S_ * HD_ * 4;
    float* tokp = (float*)w; w += (size_t)2560 * T_ * 4;
    float* posp = (float*)w; w += (size_t)B_ * H_ * S_ * 4;
    float* tokm = (float*)w; w += (size_t)B_ * T_ * 4;
    float* posm = (float*)w; w += (size_t)B_ * S_ * 4;
    unsigned short* Ahi   = (unsigned short*)w; w += (size_t)M1_ * HD_ * 2;
    unsigned short* Alo   = (unsigned short*)w; w += (size_t)M1_ * HD_ * 2;
    unsigned short* ctxb  = (unsigned short*)w; w += (size_t)M1_ * HD_ * 2;
    unsigned short* WqhiT = (unsigned short*)w; w += (size_t)C_ * HD_ * 2;
    unsigned short* WqloT = (unsigned short*)w; w += (size_t)C_ * HD_ * 2;
    unsigned short* WohiT = (unsigned short*)w; w += (size_t)HD_ * C_ * 2;
    unsigned short* WoloT = (unsigned short*)w; w += (size_t)HD_ * C_ * 2;
    (void)ws_size; (void)in_sizes; (void)n_in; (void)out_size;

    // 1. Split hidden -> bf16 hi/lo; weights -> transposed bf16 hi/lo
    split_convert_kernel<<<M1_ * HD_ / 4 / 256, 256, 0, stream>>>(hidden, Ahi, Alo);
    wsplitT_kernel<<<dim3(40, 40), 256, 0, stream>>>(Wq, WqhiT, WqloT);
    wsplitT_kernel<<<dim3(40, 40), 256, 0, stream>>>(Wo, WohiT, WoloT);
    // 2. Q projection: 8-phase 256^2 GEMM; split-bf16 via 3-segment K concat
    //    (Ah*Bh + Ah*Bl + Al*Bh), NTILES = 60.
    gemm8p_kernel<false><<<640, 512, 0, stream>>>(
        Ahi, Ahi, Alo, WqhiT, WqloT, WqhiT, q, 60, nullptr, nullptr);
    // 3. K and V projections (fp32 — feeds scoring path)
    gemm64_kernel<<<dim3(20, 10, 2), 256, 0, stream>>>(
        enc, Wk, Wv, kbuf, vbuf, MKV_, HD_, CENC_);
    // 4. First attention (MFMA) -> token-score partials
    pass_a_kernel<<<2560, 256, 0, stream>>>(q, kbuf, tokp);
    // 5. Token top-k mask
    topk_tok_kernel<<<8, 128, 0, stream>>>(tokp, tokm);
    // 6. Cross-frame K/V mixing
    mix_kernel<<<385, 256, 0, stream>>>(kbuf, vbuf, tokm, kd, v2);
    // 7. Fused pass B (pos scores) + pass C (second attention, MFMA)
    pass_bc_kernel<<<2560, 256, 0, stream>>>(q, kbuf, kd, v2, tokm, posp, ctx);
    // 8. Position top-k mask
    topk_pos_kernel<<<8, 1024, 0, stream>>>(posp, posm);
    // 9. Batch-sum of context for mean-of-others injection
    ctxsum_kernel<<<S_ * HD_ / 4 / 256, 256, 0, stream>>>(ctx, csum);
    // 10. Injection + bf16 convert of context (A operand of O-proj)
    inject_convert_kernel<<<M1_ * HD_ / 4 / 256, 256, 0, stream>>>(ctx, csum, posm, ctxb);
    // 11. O projection: 8-phase GEMM, single segment (NTILES=20), fused
    //     bias + residual epilogue.
    gemm8p_kernel<true><<<640, 512, 0, stream>>>(
        ctxb, ctxb, ctxb, WohiT, WohiT, WohiT, out, 20, bo, hidden);
}

// Round 5
// 1518.654 us; speedup vs baseline: 1.1712x; 1.1712x over previous
//
#include <hip/hip_runtime.h>
#include <math.h>

// Problem constants
#define B_    8
#define S_    4096
#define T_    77
#define C_    1280
#define CENC_ 2048
#define H_    20
#define D_    64
#define HD_   1280
#define M1_   (B_*S_)     // 32768 rows for Q / O GEMMs
#define MKV_  (B_*T_)     // 616 rows for K/V GEMM
#define KTOK_ 12          // ceil(77*0.15)
#define KPOS_ 1229        // ceil(4096*0.3)
#define SCALE_ 0.125f     // 1/sqrt(64)
#define CMIX_  0.15f      // STRENGTH*(1-ALPHA)
#define CINJ_  (0.25f/7.0f) // FIW*STRENGTH/(B-1)
#define SEGT_  20         // K-tiles (of 64) per 1280-wide segment

typedef __attribute__((ext_vector_type(8))) short bf16x8;
typedef __attribute__((ext_vector_type(4))) float f32x4;

#define AS_G __attribute__((address_space(1)))
#define AS_L __attribute__((address_space(3)))
#define MFMA16 __builtin_amdgcn_mfma_f32_16x16x32_bf16
#define SBAR() asm volatile("s_barrier" ::: "memory")
#define VM8 asm volatile("s_waitcnt vmcnt(8)" ::: "memory")
#define VM0 asm volatile("s_waitcnt vmcnt(0)" ::: "memory")
#define NOP ((void)0)

// ---------------------------------------------------------------------------
// bf16 helpers (RNE)
// ---------------------------------------------------------------------------
__device__ inline unsigned short f2bf(float x)
{
    union { float f; unsigned u; } v; v.f = x;
    const unsigned r = v.u + 0x7FFFu + ((v.u >> 16) & 1u);
    return (unsigned short)(r >> 16);
}
__device__ inline float bf2f(unsigned short h)
{
    union { float f; unsigned u; } v; v.u = ((unsigned)h) << 16;
    return v.f;
}

// split 8 consecutive fp32 -> bf16 hi + lo fragments (two aligned float4s)
__device__ inline void split_frag(const float* __restrict__ p, bf16x8& hi, bf16x8& lo)
{
    const float4 a = *(const float4*)p;
    const float4 b = *(const float4*)(p + 4);
    float f[8] = {a.x, a.y, a.z, a.w, b.x, b.y, b.z, b.w};
    #pragma unroll
    for (int e = 0; e < 8; ++e) {
        const unsigned short h = f2bf(f[e]);
        hi[e] = (short)h;
        lo[e] = (short)f2bf(f[e] - bf2f(h));
    }
}

// ---------------------------------------------------------------------------
// Split fp32 -> bf16 hi + bf16 lo (residual). One float4 per thread.
// ---------------------------------------------------------------------------
__global__ __launch_bounds__(256)
void split_convert_kernel(const float* __restrict__ x, unsigned short* __restrict__ hi,
                          unsigned short* __restrict__ lo)
{
    const size_t i4 = (size_t)blockIdx.x * 256 + threadIdx.x;
    const float4 v = ((const float4*)x)[i4];
    ushort4 h, l;
    h.x = f2bf(v.x); l.x = f2bf(v.x - bf2f(h.x));
    h.y = f2bf(v.y); l.y = f2bf(v.y - bf2f(h.y));
    h.z = f2bf(v.z); l.z = f2bf(v.z - bf2f(h.z));
    h.w = f2bf(v.w); l.w = f2bf(v.w - bf2f(h.w));
    ((ushort4*)hi)[i4] = h;
    ((ushort4*)lo)[i4] = l;
}

// ---------------------------------------------------------------------------
// Weight transpose + split: W[K=1280][N=1280] fp32 -> Thi/Tlo [N][K] bf16.
// ---------------------------------------------------------------------------
__global__ __launch_bounds__(256)
void wsplitT_kernel(const float* __restrict__ W, unsigned short* __restrict__ Thi,
                    unsigned short* __restrict__ Tlo)
{
    __shared__ float tile[32][33];
    const int tx = threadIdx.x & 31, ty = threadIdx.x >> 5;
    const int n0 = blockIdx.x * 32, k0 = blockIdx.y * 32;
    #pragma unroll
    for (int i = 0; i < 4; ++i) {
        const int kk = ty + i * 8;
        tile[kk][tx] = W[(size_t)(k0 + kk) * 1280 + n0 + tx];
    }
    __syncthreads();
    #pragma unroll
    for (int i = 0; i < 4; ++i) {
        const int nn = ty + i * 8;
        const float v = tile[tx][nn];               // = W[k0+tx][n0+nn]
        const unsigned short h = f2bf(v);
        const size_t oi = (size_t)(n0 + nn) * 1280 + k0 + tx;
        Thi[oi] = h;
        Tlo[oi] = f2bf(v - bf2f(h));
    }
}

// ---------------------------------------------------------------------------
// Injection + fp32->bf16 for the O-projection A operand:
// a = ctx*(1-8*cf) + cf*csum, cf = posm[row]*CINJ_.
// ---------------------------------------------------------------------------
__global__ __launch_bounds__(256)
void inject_convert_kernel(const float* __restrict__ ctx, const float* __restrict__ csum,
                           const float* __restrict__ posm, unsigned short* __restrict__ outb)
{
    const size_t i4 = (size_t)blockIdx.x * 256 + threadIdx.x;   // float4 index
    const int row = (int)(i4 / 320);
    const int c4  = (int)(i4 % 320);
    const float cf = posm[row] * CINJ_;
    const float am = 1.0f - 8.0f * cf;
    const float4 c  = ((const float4*)ctx)[i4];
    const float4 cs = ((const float4*)csum)[(size_t)(row & (S_ - 1)) * 320 + c4];
    ushort4 h;
    h.x = f2bf(c.x * am + cf * cs.x);
    h.y = f2bf(c.y * am + cf * cs.y);
    h.z = f2bf(c.z * am + cf * cs.z);
    h.w = f2bf(c.w * am + cf * cs.w);
    ((ushort4*)outb)[i4] = h;
}

// ---------------------------------------------------------------------------
// 8-phase 256x256 MFMA GEMM (T3+T4+T5), r4 schedule + r1 pair-packed LDS
// addressing (r4's k-chunk-major layout destroyed global coalescing: 64
// scattered 16B requests/instr -> request-rate bound; r1's layout gives 64B
// contiguous per 4 lanes AND conflict-free ds_read, both HW-verified on this
// problem in R2/R3).
//
// LDS region per (buf, ks): [128 prows][128B]; prow rr packs logical rows
// {2rr, 2rr+1}'s 64B k-slices; 16B chunk at logical (row, j) sits at pos
// (((row&1)<<2)|j) ^ (rr&7). Staging: LINEAR wave dest (chunk c -> c*16B);
// inverse involution applied to per-lane GLOBAL source: rr=c>>3,
// l=(c&7)^(rr&7), row=2rr+(l>>2), j=l&3 -> per 4 lanes one contiguous 64B
// row-segment. Fragment read at (row R, quad): rr*128 + pos*16 bytes ->
// 16 lanes span 8 bank-groups x2 = free (R2: conflicts measured 0).
//
// Schedule (unchanged from r4; units = one stage call = 2 loads/wave):
//   iter: ph1 rd b0ks0 mlo+B |stg A1ks1->b1       ph2 rd b0ks0 mhi |stg B1ks1 |VM8
//         ph3 rd b0ks1 mlo+B |stg A(t0+2)ks0->b0  ph4 ... B(t0+2)ks0 |VM8
//         ph5 rd b1ks0 mlo+B |stg A(t0+2)ks1->b0  ph6 ... B(t0+2)ks1 |VM8
//         ph7 rd b1ks1 mlo+B |stg A(t1+2)ks0->b1  ph8 ... B(t1+2)ks0 |VM8
// VM8 = 4 newest units outstanding; every unit forced-landed >=1 phase
// before its first read (ledger verified R3). Last iteration peeled w/ VM0.
// ---------------------------------------------------------------------------

// ushort offset within a (buf,ks) region for logical row R, 16B-chunk quad
__device__ inline int pswz(int R, int quad)
{
    const int rr = R >> 1;
    const int pos = (((R & 1) << 2) | quad) ^ (rr & 7);
    return rr * 64 + pos * 8;
}

#define PHASE(BUF, KS, MH, RB, STG, VM)                                         \
    {                                                                           \
        const unsigned short* SAp = sA[BUF] + (KS) * 8192;                      \
        _Pragma("unroll")                                                       \
        for (int j = 0; j < 4; ++j)                                             \
            aF[j] = *(const bf16x8*)(SAp + pswz(wr*128 + (MH)*64 + j*16 + lrow, quad)); \
        if (RB) {                                                               \
            const unsigned short* SBp = sB[BUF] + (KS) * 8192;                  \
            _Pragma("unroll")                                                   \
            for (int g = 0; g < 4; ++g)                                         \
                bF[g] = *(const bf16x8*)(SBp + pswz(wc*64 + g*16 + lrow, quad)); \
        }                                                                       \
        STG;                                                                    \
        SBAR();                                                                 \
        asm volatile("s_waitcnt lgkmcnt(0)" ::: "memory");                      \
        __builtin_amdgcn_sched_barrier(0);                                      \
        __builtin_amdgcn_s_setprio(1);                                          \
        _Pragma("unroll")                                                       \
        for (int j = 0; j < 4; ++j)                                             \
            _Pragma("unroll")                                                   \
            for (int g = 0; g < 4; ++g)                                         \
                acc[(MH)*4+j][g] = MFMA16(aF[j], bF[g], acc[(MH)*4+j][g], 0, 0, 0); \
        __builtin_amdgcn_s_setprio(0);                                          \
        VM;                                                                     \
        SBAR();                                                                 \
    }

template<bool FUSE>
__global__ __launch_bounds__(512, 2)
void gemm8p_kernel(const unsigned short* __restrict__ A0, const unsigned short* __restrict__ A1,
                   const unsigned short* __restrict__ A2,
                   const unsigned short* __restrict__ B0, const unsigned short* __restrict__ B1,
                   const unsigned short* __restrict__ B2,
                   float* __restrict__ Cout, int NTILES,
                   const float* __restrict__ bias, const float* __restrict__ resid)
{
    __shared__ unsigned short sA[2][16384];   // [buf][ks(2) x 8192 ushorts]
    __shared__ unsigned short sB[2][16384];

    const int tid  = threadIdx.x;
    const int lane = tid & 63;
    const int wid  = tid >> 6;
    const int quad = lane >> 4;
    const int lrow = lane & 15;
    const int wr = wid >> 2;          // 0..1  (m half of the 256 tile)
    const int wc = wid & 3;           // 0..3  (n quarter)

    // bijective XCD swizzle (grid % 8 == 0), then n-panel-major decomposition
    const int nwg = gridDim.x;
    const int cpx = nwg >> 3;
    int sw = ((int)blockIdx.x & 7) * cpx + ((int)blockIdx.x >> 3);
    const int m0 = (sw & 127) * 256;          // 128 m-tiles
    const int n0 = (sw >> 7) * 256;           // 5 n-tiles

    // staging: chunk c = tid + j*512 in [0,1024); pair-packed involution.
    // rr=c>>3, l=(c&7)^(rr&7), row=2rr+(l>>2), jj=l&3 -> 4 lanes = 64B segment.
    int voff[2], cdst[2];
    #pragma unroll
    for (int j = 0; j < 2; ++j) {
        const int c = tid + j * 512;
        const int rr = c >> 3;
        const int l  = (c & 7) ^ (rr & 7);
        const int row = 2 * rr + (l >> 2);
        const int jj  = l & 3;
        voff[j] = row * 1280 + jj * 8;
        cdst[j] = c * 8;
    }

    auto stageA = [&](int t, int ks) {
        const int seg = t / SEGT_;
        const int kt  = t - seg * SEGT_;
        const unsigned short* Ab = (seg == 0) ? A0 : (seg == 1) ? A1 : A2;
        const size_t base = (size_t)m0 * 1280 + kt * 64 + ks * 32;
        unsigned short* reg = &sA[t & 1][ks * 8192];
        #pragma unroll
        for (int j = 0; j < 2; ++j)
            __builtin_amdgcn_global_load_lds((const AS_G void*)(Ab + base + voff[j]),
                                             (AS_L void*)(reg + cdst[j]), 16, 0, 0);
    };
    auto stageB = [&](int t, int ks) {
        const int seg = t / SEGT_;
        const int kt  = t - seg * SEGT_;
        const unsigned short* Bb = (seg == 0) ? B0 : (seg == 1) ? B1 : B2;
        const size_t base = (size_t)n0 * 1280 + kt * 64 + ks * 32;
        unsigned short* reg = &sB[t & 1][ks * 8192];
        #pragma unroll
        for (int j = 0; j < 2; ++j)
            __builtin_amdgcn_global_load_lds((const AS_G void*)(Bb + base + voff[j]),
                                             (AS_L void*)(reg + cdst[j]), 16, 0, 0);
    };

    f32x4 acc[8][4] = {};
    bf16x8 aF[4], bF[4];

    const int NI = NTILES >> 1;               // iterations (2 tiles each); NI >= 2

    // prologue: tile0 all 4 units + tile1 ks0 units, then allow 4 newest units
    stageA(0, 0); stageB(0, 0); stageA(0, 1); stageB(0, 1); stageA(1, 0); stageB(1, 0);
    VM8;        // 6 units outstanding-cap 8 loads => oldest 2 units (tile0 ks0) landed
    SBAR();

    for (int it = 0; it < NI - 1; ++it) {
        const int t0 = 2 * it, t1 = 2 * it + 1;
        PHASE(0, 0, 0, true,  stageA(t1, 1),     NOP);
        PHASE(0, 0, 1, false, stageB(t1, 1),     VM8);
        PHASE(0, 1, 0, true,  stageA(t0 + 2, 0), NOP);
        PHASE(0, 1, 1, false, stageB(t0 + 2, 0), VM8);
        PHASE(1, 0, 0, true,  stageA(t0 + 2, 1), NOP);
        PHASE(1, 0, 1, false, stageB(t0 + 2, 1), VM8);
        PHASE(1, 1, 0, true,  stageA(t1 + 2, 0), NOP);
        PHASE(1, 1, 1, false, stageB(t1 + 2, 0), VM8);
    }
    {   // peeled last iteration: only t1's ks1 still to stage, then drain
        const int t1 = NTILES - 1;
        PHASE(0, 0, 0, true,  stageA(t1, 1), NOP);
        PHASE(0, 0, 1, false, stageB(t1, 1), VM0);
        PHASE(0, 1, 0, true,  NOP, NOP);
        PHASE(0, 1, 1, false, NOP, NOP);
        PHASE(1, 0, 0, true,  NOP, NOP);
        PHASE(1, 0, 1, false, NOP, NOP);
        PHASE(1, 1, 0, true,  NOP, NOP);
        PHASE(1, 1, 1, false, NOP, NOP);
    }

    // Epilogue: C/D layout col = lane&15, row = quad*4 + reg (m89/m91-verified)
    #pragma unroll
    for (int f = 0; f < 8; ++f) {
        #pragma unroll
        for (int g = 0; g < 4; ++g) {
            const int col = n0 + wc * 64 + g * 16 + lrow;
            #pragma unroll
            for (int r2 = 0; r2 < 4; ++r2) {
                const int row = m0 + wr * 128 + f * 16 + quad * 4 + r2;
                float v = acc[f][g][r2];
                if constexpr (FUSE)
                    v += bias[col] + resid[(size_t)row * 1280 + col];
                Cout[(size_t)row * 1280 + col] = v;
            }
        }
    }
}

// ---------------------------------------------------------------------------
// fp32 GEMM, 64x64 tile, BK=16, 256 threads, 4x4 micro-tile. For K/V
// projections (M=616, K=2048, N=1280) — stays fp32 (feeds scoring path).
// ---------------------------------------------------------------------------
__global__ __launch_bounds__(256)
void gemm64_kernel(const float* __restrict__ A,
                   const float* __restrict__ B0, const float* __restrict__ B1,
                   float* __restrict__ C0, float* __restrict__ C1,
                   int M, int N, int K)
{
    const float* Bm = blockIdx.z ? B1 : B0;
    float* Cout = blockIdx.z ? C1 : C0;
    __shared__ float As[16][64];
    __shared__ float Bs[16][64];
    const int tid = threadIdx.x;
    const int n0 = blockIdx.x * 64;
    const int m0 = blockIdx.y * 64;
    const int tx = tid & 15, ty = tid >> 4;
    const int ar = tid >> 2;
    const int ak = (tid & 3) << 2;
    const int bk = tid >> 4;
    const int bn = (tid & 15) << 2;

    float acc[4][4] = {};
    const int arow = m0 + ar;
    const bool avalid = arow < M;
    const float* Ap = A + (size_t)arow * K + ak;
    const float* Bp = Bm + (size_t)bk * N + n0 + bn;

    for (int k0 = 0; k0 < K; k0 += 16) {
        const float4 a = avalid ? *(const float4*)(Ap + k0) : make_float4(0.f,0.f,0.f,0.f);
        const float4 b = *(const float4*)(Bp + (size_t)k0 * N);
        __syncthreads();
        As[ak+0][ar] = a.x; As[ak+1][ar] = a.y; As[ak+2][ar] = a.z; As[ak+3][ar] = a.w;
        *(float4*)&Bs[bk][bn] = b;
        __syncthreads();
        #pragma unroll
        for (int kk = 0; kk < 16; ++kk) {
            const float4 av = *(const float4*)&As[kk][ty*4];
            const float4 bv = *(const float4*)&Bs[kk][tx*4];
            const float arr[4] = {av.x, av.y, av.z, av.w};
            const float brr[4] = {bv.x, bv.y, bv.z, bv.w};
            #pragma unroll
            for (int r = 0; r < 4; ++r)
                #pragma unroll
                for (int c = 0; c < 4; ++c)
                    acc[r][c] = fmaf(arr[r], brr[c], acc[r][c]);
        }
    }
    #pragma unroll
    for (int r = 0; r < 4; ++r) {
        const int row = m0 + ty * 4 + r;
        if (row < M) {
            const float4 cv = make_float4(acc[r][0], acc[r][1], acc[r][2], acc[r][3]);
            *(float4*)(Cout + (size_t)row * N + n0 + tx * 4) = cv;
        }
    }
}

__device__ inline bool first_pair(float va, int ia, float vb, int ib)
{
    return (va > vb) || (va == vb && ia < ib);
}

// descending by (value, then index asc) — matches lax.top_k tie-break
__device__ inline void bitonic_desc(float* vals, int* idxs, int n, int tid, int nt)
{
    for (int k = 2; k <= n; k <<= 1) {
        for (int j = k >> 1; j > 0; j >>= 1) {
            __syncthreads();
            for (int i = tid; i < n; i += nt) {
                const int l = i ^ j;
                if (l > i) {
                    const float vi = vals[i], vl = vals[l];
                    const int   ii = idxs[i], il = idxs[l];
                    const bool up = (i & k) == 0;
                    const bool sw = up ? first_pair(vl, il, vi, ii)
                                       : first_pair(vi, ii, vl, il);
                    if (sw) { vals[i] = vl; vals[l] = vi; idxs[i] = il; idxs[l] = ii; }
                }
            }
        }
    }
    __syncthreads();
}

// ---------------------------------------------------------------------------
// Pass A (MFMA): swapped QK^T -> per-lane logits for 16 s-cols (s = lane&15),
// t = nt*16 + quad*4 + r. 4-product split bf16 QK (fp32-level accuracy; the
// logits feed the top-k masks, which must not flip). Softmax over t = register
// max/sum + shfl_xor(16/32) quad reduce. Accumulate sum_s p per t -> tokp.
// Grid: 2560 blocks = b(8) x h(20) x s-chunk(16); 4 waves x 4 s-tiles = 256 s.
// ---------------------------------------------------------------------------
__global__ __launch_bounds__(256)
void pass_a_kernel(const float* __restrict__ q, const float* __restrict__ kbuf,
                   float* __restrict__ tokp)
{
    __shared__ unsigned short khi[80 * 64];   // [t][d] bf16, XOR-swizzled rows
    __shared__ unsigned short klo[80 * 64];
    __shared__ float wsum[4][80];
    const int g = blockIdx.x;
    const int b = g / 320;
    const int rem = g % 320;
    const int h = rem >> 4;
    const int chunk = rem & 15;
    const int tid = threadIdx.x;

    // stage K slice -> swizzled bf16 hi/lo (T2 swizzle: byte ^= (t&7)<<4)
    for (int i = tid; i < 80 * 16; i += 256) {
        const int t = i >> 4, j = i & 15;                 // d0 = 4*j
        float4 v = make_float4(0.f, 0.f, 0.f, 0.f);
        if (t < T_) v = *(const float4*)(kbuf + (size_t)(b * T_ + t) * HD_ + h * D_ + 4 * j);
        ushort4 hh, ll;
        hh.x = f2bf(v.x); ll.x = f2bf(v.x - bf2f(hh.x));
        hh.y = f2bf(v.y); ll.y = f2bf(v.y - bf2f(hh.y));
        hh.z = f2bf(v.z); ll.z = f2bf(v.z - bf2f(hh.z));
        hh.w = f2bf(v.w); ll.w = f2bf(v.w - bf2f(hh.w));
        const int byt = t * 128 + ((8 * j) ^ ((t & 7) << 4));
        *(ushort4*)((char*)khi + byt) = hh;
        *(ushort4*)((char*)klo + byt) = ll;
    }
    __syncthreads();

    const int wid = tid >> 6, lane = tid & 63;
    const int lrow = lane & 15, quad = lane >> 4;

    f32x4 tokacc[5] = {};
    for (int st = 0; st < 4; ++st) {
        const int s = chunk * 256 + wid * 64 + st * 16 + lrow;
        const float* qp = q + (size_t)(b * S_ + s) * HD_ + h * D_;
        bf16x8 qhi[2], qlo[2];
        #pragma unroll
        for (int ks = 0; ks < 2; ++ks)
            split_frag(qp + ks * 32 + quad * 8, qhi[ks], qlo[ks]);

        f32x4 acc[5] = {};
        #pragma unroll
        for (int nt = 0; nt < 5; ++nt) {
            #pragma unroll
            for (int ks = 0; ks < 2; ++ks) {
                const int krow = nt * 16 + lrow;
                const int byt = krow * 128 + ((64 * ks + 16 * quad) ^ ((krow & 7) << 4));
                const bf16x8 kh = *(const bf16x8*)((const char*)khi + byt);
                const bf16x8 kl = *(const bf16x8*)((const char*)klo + byt);
                acc[nt] = MFMA16(kh, qhi[ks], acc[nt], 0, 0, 0);
                acc[nt] = MFMA16(kh, qlo[ks], acc[nt], 0, 0, 0);
                acc[nt] = MFMA16(kl, qhi[ks], acc[nt], 0, 0, 0);
                acc[nt] = MFMA16(kl, qlo[ks], acc[nt], 0, 0, 0);
            }
        }
        float m = -1e30f;
        #pragma unroll
        for (int nt = 0; nt < 5; ++nt)
            #pragma unroll
            for (int r = 0; r < 4; ++r) {
                const int t = nt * 16 + quad * 4 + r;
                const float l = (t < T_) ? acc[nt][r] * SCALE_ : -1e30f;
                acc[nt][r] = l;
                m = fmaxf(m, l);
            }
        m = fmaxf(m, __shfl_xor(m, 16, 64));
        m = fmaxf(m, __shfl_xor(m, 32, 64));
        float Lp = 0.f;
        #pragma unroll
        for (int nt = 0; nt < 5; ++nt)
            #pragma unroll
            for (int r = 0; r < 4; ++r) {
                const float e = __expf(acc[nt][r] - m);
                acc[nt][r] = e;
                Lp += e;
            }
        float L = Lp + __shfl_xor(Lp, 16, 64);
        L += __shfl_xor(L, 32, 64);
        const float invL = 1.0f / L;
        #pragma unroll
        for (int nt = 0; nt < 5; ++nt)
            #pragma unroll
            for (int r = 0; r < 4; ++r)
                tokacc[nt][r] = fmaf(acc[nt][r], invL, tokacc[nt][r]);
    }
    // reduce over the 16 s-columns (lane bits 0..3), write per-wave partials
    #pragma unroll
    for (int nt = 0; nt < 5; ++nt)
        #pragma unroll
        for (int r = 0; r < 4; ++r) {
            float v = tokacc[nt][r];
            v += __shfl_xor(v, 1, 64);
            v += __shfl_xor(v, 2, 64);
            v += __shfl_xor(v, 4, 64);
            v += __shfl_xor(v, 8, 64);
            if (lrow == 0) wsum[wid][nt * 16 + quad * 4 + r] = v;
        }
    __syncthreads();
    for (int t = tid; t < T_; t += 256)
        tokp[(size_t)g * T_ + t] = (wsum[0][t] + wsum[1][t]) + (wsum[2][t] + wsum[3][t]);
}

// ---------------------------------------------------------------------------
// Top-k over 77 token scores per batch -> tok_mask. 8 blocks x 128 threads.
// ---------------------------------------------------------------------------
__global__ __launch_bounds__(128)
void topk_tok_kernel(const float* __restrict__ tokp, float* __restrict__ tokm)
{
    __shared__ float vals[128];
    __shared__ int idxs[128];
    const int b = blockIdx.x, tid = threadIdx.x;
    float v = -1e30f;
    if (tid < T_) {
        float sm = 0.f;
        for (int j = 0; j < 320; ++j) sm += tokp[(size_t)(b * 320 + j) * T_ + tid];
        v = sm;
    }
    vals[tid] = v; idxs[tid] = tid;
    bitonic_desc(vals, idxs, 128, tid, 128);
    if (tid < T_) tokm[b * T_ + tid] = 0.f;
    __syncthreads();
    if (tid < KTOK_) tokm[b * T_ + idxs[tid]] = 1.0f;
}

// ---------------------------------------------------------------------------
// K/V cross-frame mixing: kd = k2-k (delta, mask folded in), v2 = mixed v.
// ---------------------------------------------------------------------------
__global__ __launch_bounds__(256)
void mix_kernel(const float* __restrict__ kbuf, const float* __restrict__ vbuf,
                const float* __restrict__ tokm,
                float* __restrict__ kd, float* __restrict__ v2)
{
    const int i = blockIdx.x * 256 + threadIdx.x;   // < 77*1280 = 98560
    const int t = i / HD_;
    float ks = 0.f, vs = 0.f;
    #pragma unroll
    for (int b = 0; b < B_; ++b) {
        ks += kbuf[(size_t)b * T_ * HD_ + i];
        vs += vbuf[(size_t)b * T_ * HD_ + i];
    }
    #pragma unroll
    for (int b = 0; b < B_; ++b) {
        const size_t gi = (size_t)b * T_ * HD_ + i;
        const float msk = tokm[b * T_ + t];
        const float kx = kbuf[gi], vx = vbuf[gi];
        kd[gi] = CMIX_ * msk * ((ks - 8.f * kx) * (1.0f / 7.0f));
        v2[gi] = vx + CMIX_ * msk * ((vs - 8.f * vx) * (1.0f / 7.0f));
    }
}

// ---------------------------------------------------------------------------
// Fused pass B+C (MFMA): swapped QK^T gives per-lane l1 (split, 4 products)
// and l2 = l1 + q·kd (kd bf16-hi; mask folded into kd). Register softmax for
// both; posp = masked mass of softmax(l1); p2 = softmax(l2) -> LDS round-trip
// per 32-wide k-step (hi/lo) -> swapped PV mfma(V^T, P) -> ctx.
// ---------------------------------------------------------------------------
__global__ __launch_bounds__(256)
void pass_bc_kernel(const float* __restrict__ q, const float* __restrict__ kbuf,
                    const float* __restrict__ kd, const float* __restrict__ v2,
                    const float* __restrict__ tokm,
                    float* __restrict__ posp, float* __restrict__ ctx)
{
    __shared__ unsigned short khi[80 * 64];     // [t][d] XOR-swizzled
    __shared__ unsigned short klo[80 * 64];
    __shared__ unsigned short kdh[80 * 64];
    __shared__ unsigned short vThi[64 * 88];    // [d][t] rows padded to 88
    __shared__ unsigned short vTlo[64 * 88];
    __shared__ unsigned short vguard[128];      // zeroed guard for vT overreads
    __shared__ unsigned short Pbuf[4][2][16 * 40]; // per-wave [hi/lo][s][tloc]
    __shared__ float smaskf[80];

    const int g = blockIdx.x;
    const int b = g / 320;
    const int rem = g % 320;
    const int h = rem >> 4;
    const int chunk = rem & 15;
    const int tid = threadIdx.x;

    // ---- stage K (hi/lo) + Kd (hi), swizzled ----
    for (int i = tid; i < 80 * 16; i += 256) {
        const int t = i >> 4, j = i & 15;
        float4 vk = make_float4(0.f, 0.f, 0.f, 0.f);
        float4 vd = make_float4(0.f, 0.f, 0.f, 0.f);
        if (t < T_) {
            const size_t gi = (size_t)(b * T_ + t) * HD_ + h * D_ + 4 * j;
            vk = *(const float4*)(kbuf + gi);
            vd = *(const float4*)(kd + gi);
        }
        ushort4 hh, ll, dd;
        hh.x = f2bf(vk.x); ll.x = f2bf(vk.x - bf2f(hh.x)); dd.x = f2bf(vd.x);
        hh.y = f2bf(vk.y); ll.y = f2bf(vk.y - bf2f(hh.y)); dd.y = f2bf(vd.y);
        hh.z = f2bf(vk.z); ll.z = f2bf(vk.z - bf2f(hh.z)); dd.z = f2bf(vd.z);
        hh.w = f2bf(vk.w); ll.w = f2bf(vk.w - bf2f(hh.w)); dd.w = f2bf(vd.w);
        const int byt = t * 128 + ((8 * j) ^ ((t & 7) << 4));
        *(ushort4*)((char*)khi + byt) = hh;
        *(ushort4*)((char*)klo + byt) = ll;
        *(ushort4*)((char*)kdh + byt) = dd;
    }
    // ---- stage V^T (hi/lo): rows d (88 cols, zero-padded past t=76) ----
    for (int i = tid; i < 64 * 22; i += 256) {
        const int d = i / 22, jg = i - d * 22;           // cols t = 4*jg..+3
        float vv[4];
        #pragma unroll
        for (int r = 0; r < 4; ++r) {
            const int t = 4 * jg + r;
            vv[r] = (t < T_) ? v2[(size_t)(b * T_ + t) * HD_ + h * D_ + d] : 0.f;
        }
        ushort4 hh, ll;
        hh.x = f2bf(vv[0]); ll.x = f2bf(vv[0] - bf2f(hh.x));
        hh.y = f2bf(vv[1]); ll.y = f2bf(vv[1] - bf2f(hh.y));
        hh.z = f2bf(vv[2]); ll.z = f2bf(vv[2] - bf2f(hh.z));
        hh.w = f2bf(vv[3]); ll.w = f2bf(vv[3] - bf2f(hh.w));
        const int byt = d * 176 + 8 * jg;
        *(ushort4*)((char*)vThi + byt) = hh;
        *(ushort4*)((char*)vTlo + byt) = ll;
    }
    for (int t = tid; t < 80; t += 256) smaskf[t] = (t < T_) ? tokm[b * T_ + t] : 0.f;
    for (int i = tid; i < 128; i += 256) vguard[i] = 0;
    __syncthreads();

    const int wid = tid >> 6, lane = tid & 63;
    const int lrow = lane & 15, quad = lane >> 4;
    unsigned short* Ph = &Pbuf[wid][0][0];
    unsigned short* Pl = &Pbuf[wid][1][0];

    // hoist per-lane token-mask values (constant across s-tiles)
    float smv[5][4];
    #pragma unroll
    for (int nt = 0; nt < 5; ++nt)
        #pragma unroll
        for (int r = 0; r < 4; ++r)
            smv[nt][r] = smaskf[nt * 16 + quad * 4 + r];

    for (int st = 0; st < 4; ++st) {
        const int s = chunk * 256 + wid * 64 + st * 16 + lrow;
        const float* qp = q + (size_t)(b * S_ + s) * HD_ + h * D_;
        bf16x8 qhi[2], qlo[2];
        #pragma unroll
        for (int ks = 0; ks < 2; ++ks)
            split_frag(qp + ks * 32 + quad * 8, qhi[ks], qlo[ks]);

        f32x4 acc1[5] = {}, accd[5] = {};
        #pragma unroll
        for (int nt = 0; nt < 5; ++nt) {
            #pragma unroll
            for (int ks = 0; ks < 2; ++ks) {
                const int krow = nt * 16 + lrow;
                const int byt = krow * 128 + ((64 * ks + 16 * quad) ^ ((krow & 7) << 4));
                const bf16x8 kh = *(const bf16x8*)((const char*)khi + byt);
                const bf16x8 kl = *(const bf16x8*)((const char*)klo + byt);
                const bf16x8 kdv = *(const bf16x8*)((const char*)kdh + byt);
                acc1[nt] = MFMA16(kh, qhi[ks], acc1[nt], 0, 0, 0);
                acc1[nt] = MFMA16(kh, qlo[ks], acc1[nt], 0, 0, 0);
                acc1[nt] = MFMA16(kl, qhi[ks], acc1[nt], 0, 0, 0);
                acc1[nt] = MFMA16(kl, qlo[ks], acc1[nt], 0, 0, 0);
                accd[nt] = MFMA16(kdv, qhi[ks], accd[nt], 0, 0, 0);
            }
        }

        // logits + dual softmax (l1: pos score; l2: second attention)
        float m1 = -1e30f, m2 = -1e30f;
        f32x4 l2v[5];
        #pragma unroll
        for (int nt = 0; nt < 5; ++nt)
            #pragma unroll
            for (int r = 0; r < 4; ++r) {
                const int t = nt * 16 + quad * 4 + r;
                const bool valid = t < T_;
                const float l1 = valid ? acc1[nt][r] * SCALE_ : -1e30f;
                const float l2 = valid ? l1 + accd[nt][r] * SCALE_ : -1e30f;
                acc1[nt][r] = l1;
                l2v[nt][r] = l2;
                m1 = fmaxf(m1, l1);
                m2 = fmaxf(m2, l2);
            }
        m1 = fmaxf(m1, __shfl_xor(m1, 16, 64));
        m1 = fmaxf(m1, __shfl_xor(m1, 32, 64));
        m2 = fmaxf(m2, __shfl_xor(m2, 16, 64));
        m2 = fmaxf(m2, __shfl_xor(m2, 32, 64));
        float L1p = 0.f, Smp = 0.f, L2p = 0.f;
        #pragma unroll
        for (int nt = 0; nt < 5; ++nt)
            #pragma unroll
            for (int r = 0; r < 4; ++r) {
                const float e1 = __expf(acc1[nt][r] - m1);
                L1p += e1;
                Smp = fmaf(e1, smv[nt][r], Smp);
                const float e2 = __expf(l2v[nt][r] - m2);
                l2v[nt][r] = e2;
                L2p += e2;
            }
        float L1 = L1p + __shfl_xor(L1p, 16, 64); L1 += __shfl_xor(L1, 32, 64);
        float Sm = Smp + __shfl_xor(Smp, 16, 64); Sm += __shfl_xor(Sm, 32, 64);
        float L2 = L2p + __shfl_xor(L2p, 16, 64); L2 += __shfl_xor(L2, 32, 64);
        if (quad == 0) posp[(size_t)(b * H_ + h) * S_ + s] = Sm / L1;
        const float invL2 = 1.0f / L2;
        #pragma unroll
        for (int nt = 0; nt < 5; ++nt)
            #pragma unroll
            for (int r = 0; r < 4; ++r)
                l2v[nt][r] *= invL2;

        // PV: per 32-wide k-step, P -> LDS (hi/lo) -> B-frags, V^T A-frags
        f32x4 pv[4] = {};
        #pragma unroll
        for (int ks = 0; ks < 3; ++ks) {
            asm volatile("s_waitcnt lgkmcnt(0)" ::: "memory");
            __builtin_amdgcn_sched_barrier(0);
            #pragma unroll
            for (int half = 0; half < 2; ++half) {
                const int nt = 2 * ks + half;
                ushort4 ph = {0, 0, 0, 0}, plw = {0, 0, 0, 0};
                if (nt < 5) {
                    ph.x = f2bf(l2v[nt][0]); plw.x = f2bf(l2v[nt][0] - bf2f(ph.x));
                    ph.y = f2bf(l2v[nt][1]); plw.y = f2bf(l2v[nt][1] - bf2f(ph.y));
                    ph.z = f2bf(l2v[nt][2]); plw.z = f2bf(l2v[nt][2] - bf2f(ph.z));
                    ph.w = f2bf(l2v[nt][3]); plw.w = f2bf(l2v[nt][3] - bf2f(ph.w));
                }
                const int pb = lrow * 80 + 32 * half + 8 * quad;
                *(ushort4*)((char*)Ph + pb) = ph;
                *(ushort4*)((char*)Pl + pb) = plw;
            }
            asm volatile("s_waitcnt lgkmcnt(0)" ::: "memory");
            __builtin_amdgcn_sched_barrier(0);
            const bf16x8 pH = *(const bf16x8*)((const char*)Ph + lrow * 80 + quad * 16);
            const bf16x8 pL = *(const bf16x8*)((const char*)Pl + lrow * 80 + quad * 16);
            #pragma unroll
            for (int mt = 0; mt < 4; ++mt) {
                const int vb = (mt * 16 + lrow) * 176 + 64 * ks + 16 * quad;
                const bf16x8 vH = *(const bf16x8*)((const char*)vThi + vb);
                const bf16x8 vL = *(const bf16x8*)((const char*)vTlo + vb);
                pv[mt] = MFMA16(vH, pH, pv[mt], 0, 0, 0);
                pv[mt] = MFMA16(vH, pL, pv[mt], 0, 0, 0);
                pv[mt] = MFMA16(vL, pH, pv[mt], 0, 0, 0);
            }
        }
        // ctx write: col = lane&15 = s, row(d) = mt*16 + quad*4 + reg
        float* cp = ctx + (size_t)(b * S_ + s) * HD_ + h * D_;
        #pragma unroll
        for (int mt = 0; mt < 4; ++mt) {
            const float4 o = make_float4(pv[mt][0], pv[mt][1], pv[mt][2], pv[mt][3]);
            *(float4*)(cp + mt * 16 + quad * 4) = o;
        }
    }
}

// ---------------------------------------------------------------------------
// Top-k over 4096 position scores per batch -> pos_mask. 8 blocks x 1024.
// ---------------------------------------------------------------------------
__global__ __launch_bounds__(1024)
void topk_pos_kernel(const float* __restrict__ posp, float* __restrict__ posm)
{
    __shared__ float vals[S_];
    __shared__ int idxs[S_];
    const int b = blockIdx.x, tid = threadIdx.x;
    for (int s = tid; s < S_; s += 1024) {
        float sm = 0.f;
        for (int h = 0; h < H_; ++h) sm += posp[(size_t)(b * H_ + h) * S_ + s];
        vals[s] = sm; idxs[s] = s;
    }
    bitonic_desc(vals, idxs, S_, tid, 1024);
    for (int s = tid; s < S_; s += 1024) posm[b * S_ + s] = 0.f;
    __syncthreads();
    for (int i = tid; i < KPOS_; i += 1024) posm[b * S_ + idxs[i]] = 1.0f;
}

// ---------------------------------------------------------------------------
// Batch-sum of context over b: csum[s,hd] = sum_b ctx[b,s,hd]. float4 lanes.
// ---------------------------------------------------------------------------
__global__ __launch_bounds__(256)
void ctxsum_kernel(const float* __restrict__ ctx, float* __restrict__ csum)
{
    const size_t i = (size_t)blockIdx.x * 256 + threadIdx.x;  // float4 index
    const float4* c = (const float4*)ctx;
    float4 a = c[i];
    #pragma unroll
    for (int b = 1; b < B_; ++b) {
        const float4 x = c[(size_t)b * (S_ * HD_ / 4) + i];
        a.x += x.x; a.y += x.y; a.z += x.z; a.w += x.w;
    }
    ((float4*)csum)[i] = a;
}

// ---------------------------------------------------------------------------
extern "C" void kernel_launch(void* const* d_in, const int* in_sizes, int n_in,
                              void* d_out, int out_size, void* d_ws, size_t ws_size,
                              hipStream_t stream)
{
    const float* hidden = (const float*)d_in[0];
    const float* enc    = (const float*)d_in[1];
    const float* Wq     = (const float*)d_in[2];
    const float* Wk     = (const float*)d_in[3];
    const float* Wv     = (const float*)d_in[4];
    const float* Wo     = (const float*)d_in[5];
    const float* bo     = (const float*)d_in[6];
    float* out = (float*)d_out;

    char* w = (char*)d_ws;
    float* q    = (float*)w; w += (size_t)M1_ * HD_ * 4;
    float* ctx  = (float*)w; w += (size_t)M1_ * HD_ * 4;
    float* kbuf = (float*)w; w += (size_t)B_ * T_ * HD_ * 4;
    float* vbuf = (float*)w; w += (size_t)B_ * T_ * HD_ * 4;
    float* kd   = (float*)w; w += (size_t)B_ * T_ * HD_ * 4;
    float* v2   = (float*)w; w += (size_t)B_ * T_ * HD_ * 4;
    float* csum = (float*)w; w += (size_t)S_ * HD_ * 4;
    float* tokp = (float*)w; w += (size_t)2560 * T_ * 4;
    float* posp = (float*)w; w += (size_t)B_ * H_ * S_ * 4;
    float* tokm = (float*)w; w += (size_t)B_ * T_ * 4;
    float* posm = (float*)w; w += (size_t)B_ * S_ * 4;
    unsigned short* Ahi   = (unsigned short*)w; w += (size_t)M1_ * HD_ * 2;
    unsigned short* Alo   = (unsigned short*)w; w += (size_t)M1_ * HD_ * 2;
    unsigned short* ctxb  = (unsigned short*)w; w += (size_t)M1_ * HD_ * 2;
    unsigned short* WqhiT = (unsigned short*)w; w += (size_t)C_ * HD_ * 2;
    unsigned short* WqloT = (unsigned short*)w; w += (size_t)C_ * HD_ * 2;
    unsigned short* WohiT = (unsigned short*)w; w += (size_t)HD_ * C_ * 2;
    unsigned short* WoloT = (unsigned short*)w; w += (size_t)HD_ * C_ * 2;
    (void)ws_size; (void)in_sizes; (void)n_in; (void)out_size;

    // 1. Split hidden -> bf16 hi/lo; weights -> transposed bf16 hi/lo
    split_convert_kernel<<<M1_ * HD_ / 4 / 256, 256, 0, stream>>>(hidden, Ahi, Alo);
    wsplitT_kernel<<<dim3(40, 40), 256, 0, stream>>>(Wq, WqhiT, WqloT);
    wsplitT_kernel<<<dim3(40, 40), 256, 0, stream>>>(Wo, WohiT, WoloT);
    // 2. Q projection: 8-phase 256^2 GEMM; split-bf16 via 3-segment K concat
    //    (Ah*Bh + Ah*Bl + Al*Bh), NTILES = 60.
    gemm8p_kernel<false><<<640, 512, 0, stream>>>(
        Ahi, Ahi, Alo, WqhiT, WqloT, WqhiT, q, 60, nullptr, nullptr);
    // 3. K and V projections (fp32 — feeds scoring path)
    gemm64_kernel<<<dim3(20, 10, 2), 256, 0, stream>>>(
        enc, Wk, Wv, kbuf, vbuf, MKV_, HD_, CENC_);
    // 4. First attention (MFMA) -> token-score partials
    pass_a_kernel<<<2560, 256, 0, stream>>>(q, kbuf, tokp);
    // 5. Token top-k mask
    topk_tok_kernel<<<8, 128, 0, stream>>>(tokp, tokm);
    // 6. Cross-frame K/V mixing
    mix_kernel<<<385, 256, 0, stream>>>(kbuf, vbuf, tokm, kd, v2);
    // 7. Fused pass B (pos scores) + pass C (second attention, MFMA)
    pass_bc_kernel<<<2560, 256, 0, stream>>>(q, kbuf, kd, v2, tokm, posp, ctx);
    // 8. Position top-k mask
    topk_pos_kernel<<<8, 1024, 0, stream>>>(posp, posm);
    // 9. Batch-sum of context for mean-of-others injection
    ctxsum_kernel<<<S_ * HD_ / 4 / 256, 256, 0, stream>>>(ctx, csum);
    // 10. Injection + bf16 convert of context (A operand of O-proj)
    inject_convert_kernel<<<M1_ * HD_ / 4 / 256, 256, 0, stream>>>(ctx, csum, posm, ctxb);
    // 11. O projection: 8-phase GEMM, single segment (NTILES=20), fused
    //     bias + residual epilogue.
    gemm8p_kernel<true><<<640, 512, 0, stream>>>(
        ctxb, ctxb, ctxb, WohiT, WohiT, WohiT, out, 20, bo, hidden);
}

// Round 6
// 1512.984 us; speedup vs baseline: 1.1756x; 1.0037x over previous
//
#include <hip/hip_runtime.h>
#include <math.h>

// Problem constants
#define B_    8
#define S_    4096
#define T_    77
#define C_    1280
#define CENC_ 2048
#define H_    20
#define D_    64
#define HD_   1280
#define M1_   (B_*S_)     // 32768 rows for Q / O GEMMs
#define MKV_  (B_*T_)     // 616 rows for K/V GEMM
#define KTOK_ 12          // ceil(77*0.15)
#define KPOS_ 1229        // ceil(4096*0.3)
#define SCALE_ 0.125f     // 1/sqrt(64)
#define CMIX_  0.15f      // STRENGTH*(1-ALPHA)
#define CINJ_  (0.25f/7.0f) // FIW*STRENGTH/(B-1)
#define SEGT_  20         // K-tiles (of 64) per 1280-wide segment

typedef __attribute__((ext_vector_type(8))) short bf16x8;
typedef __attribute__((ext_vector_type(4))) float f32x4;

#define AS_G __attribute__((address_space(1)))
#define AS_L __attribute__((address_space(3)))
#define MFMA16 __builtin_amdgcn_mfma_f32_16x16x32_bf16
#define SBAR() asm volatile("s_barrier" ::: "memory")
#define VM8 asm volatile("s_waitcnt vmcnt(8)" ::: "memory")
#define VM0 asm volatile("s_waitcnt vmcnt(0)" ::: "memory")
#define NOP ((void)0)

// ---------------------------------------------------------------------------
// bf16 helpers (RNE)
// ---------------------------------------------------------------------------
__device__ inline unsigned short f2bf(float x)
{
    union { float f; unsigned u; } v; v.f = x;
    const unsigned r = v.u + 0x7FFFu + ((v.u >> 16) & 1u);
    return (unsigned short)(r >> 16);
}
__device__ inline float bf2f(unsigned short h)
{
    union { float f; unsigned u; } v; v.u = ((unsigned)h) << 16;
    return v.f;
}

// split 8 consecutive fp32 -> bf16 hi + lo fragments (two aligned float4s)
__device__ inline void split_frag(const float* __restrict__ p, bf16x8& hi, bf16x8& lo)
{
    const float4 a = *(const float4*)p;
    const float4 b = *(const float4*)(p + 4);
    float f[8] = {a.x, a.y, a.z, a.w, b.x, b.y, b.z, b.w};
    #pragma unroll
    for (int e = 0; e < 8; ++e) {
        const unsigned short h = f2bf(f[e]);
        hi[e] = (short)h;
        lo[e] = (short)f2bf(f[e] - bf2f(h));
    }
}

// ---------------------------------------------------------------------------
// Split fp32 -> bf16 hi + bf16 lo (residual). One float4 per thread.
// ---------------------------------------------------------------------------
__global__ __launch_bounds__(256)
void split_convert_kernel(const float* __restrict__ x, unsigned short* __restrict__ hi,
                          unsigned short* __restrict__ lo)
{
    const size_t i4 = (size_t)blockIdx.x * 256 + threadIdx.x;
    const float4 v = ((const float4*)x)[i4];
    ushort4 h, l;
    h.x = f2bf(v.x); l.x = f2bf(v.x - bf2f(h.x));
    h.y = f2bf(v.y); l.y = f2bf(v.y - bf2f(h.y));
    h.z = f2bf(v.z); l.z = f2bf(v.z - bf2f(h.z));
    h.w = f2bf(v.w); l.w = f2bf(v.w - bf2f(h.w));
    ((ushort4*)hi)[i4] = h;
    ((ushort4*)lo)[i4] = l;
}

// ---------------------------------------------------------------------------
// Weight transpose + split: W[K=1280][N=1280] fp32 -> Thi/Tlo [N][K] bf16.
// ---------------------------------------------------------------------------
__global__ __launch_bounds__(256)
void wsplitT_kernel(const float* __restrict__ W, unsigned short* __restrict__ Thi,
                    unsigned short* __restrict__ Tlo)
{
    __shared__ float tile[32][33];
    const int tx = threadIdx.x & 31, ty = threadIdx.x >> 5;
    const int n0 = blockIdx.x * 32, k0 = blockIdx.y * 32;
    #pragma unroll
    for (int i = 0; i < 4; ++i) {
        const int kk = ty + i * 8;
        tile[kk][tx] = W[(size_t)(k0 + kk) * 1280 + n0 + tx];
    }
    __syncthreads();
    #pragma unroll
    for (int i = 0; i < 4; ++i) {
        const int nn = ty + i * 8;
        const float v = tile[tx][nn];               // = W[k0+tx][n0+nn]
        const unsigned short h = f2bf(v);
        const size_t oi = (size_t)(n0 + nn) * 1280 + k0 + tx;
        Thi[oi] = h;
        Tlo[oi] = f2bf(v - bf2f(h));
    }
}

// ---------------------------------------------------------------------------
// Injection + fp32->bf16 for the O-projection A operand:
// a = ctx*(1-8*cf) + cf*csum, cf = posm[row]*CINJ_.
// ---------------------------------------------------------------------------
__global__ __launch_bounds__(256)
void inject_convert_kernel(const float* __restrict__ ctx, const float* __restrict__ csum,
                           const float* __restrict__ posm, unsigned short* __restrict__ outb)
{
    const size_t i4 = (size_t)blockIdx.x * 256 + threadIdx.x;   // float4 index
    const int row = (int)(i4 / 320);
    const int c4  = (int)(i4 % 320);
    const float cf = posm[row] * CINJ_;
    const float am = 1.0f - 8.0f * cf;
    const float4 c  = ((const float4*)ctx)[i4];
    const float4 cs = ((const float4*)csum)[(size_t)(row & (S_ - 1)) * 320 + c4];
    ushort4 h;
    h.x = f2bf(c.x * am + cf * cs.x);
    h.y = f2bf(c.y * am + cf * cs.y);
    h.z = f2bf(c.z * am + cf * cs.z);
    h.w = f2bf(c.w * am + cf * cs.w);
    ((ushort4*)outb)[i4] = h;
}

// ---------------------------------------------------------------------------
// 8-phase 256x256 MFMA GEMM (T3+T4+T5), r5 block order.
// C[M x 1280] = sum over 3 segments of Aseg[M x 1280] * Bseg^T (split-bf16
// 3-product sum via K-segment concat; O-proj uses seg 0 only, NTILES=20).
//
// r5: n-FASTEST tile order. R2-R5 showed dur == hbm_bytes/hbm_gbps in every
// config: the GEMM tracks HBM traffic, and m-fastest order streamed each A
// panel up to 5x from HBM (FETCH 665MB vs 175MB compulsory). With n-fastest
// (sw = m*5 + n), the 5 blocks sharing an A m-panel are adjacent in sw ->
// same XCD chunk, temporally close -> A re-reads hit L2/L3. B (6.5MB total)
// is cache-resident regardless.
//
// LDS region per (buf, ks): [128 prows][128B]; prow rr packs logical rows
// {2rr, 2rr+1}'s 64B k-slices; 16B chunk at logical (row, j) sits at pos
// (((row&1)<<2)|j) ^ (rr&7). Staging: LINEAR wave dest; inverse involution
// on the per-lane GLOBAL source -> 64B contiguous per 4 lanes (coalesced)
// AND conflict-free ds_read (R2: conflicts measured 0).
//
// Schedule (ledger verified R3/R5; units = one stage call = 2 loads/wave):
//   iter: ph1 rd b0ks0 mlo+B |stg A(t1,1)      ph2 rd b0ks0 mhi |stg B(t1,1) |VM8
//         ph3 rd b0ks1 mlo+B |stg A(t0+2,0)    ph4 ... B(t0+2,0) |VM8
//         ph5 rd b1ks0 mlo+B |stg A(t0+2,1)    ph6 ... B(t0+2,1) |VM8
//         ph7 rd b1ks1 mlo+B |stg A(t1+2,0)    ph8 ... B(t1+2,0) |VM8
// VM8 = 4 newest units outstanding; every unit forced-landed >=1 phase
// before its first read. Last iteration peeled w/ VM0 drain.
// ---------------------------------------------------------------------------

// ushort offset within a (buf,ks) region for logical row R, 16B-chunk quad
__device__ inline int pswz(int R, int quad)
{
    const int rr = R >> 1;
    const int pos = (((R & 1) << 2) | quad) ^ (rr & 7);
    return rr * 64 + pos * 8;
}

#define PHASE(BUF, KS, MH, RB, STG, VM)                                         \
    {                                                                           \
        const unsigned short* SAp = sA[BUF] + (KS) * 8192;                      \
        _Pragma("unroll")                                                       \
        for (int j = 0; j < 4; ++j)                                             \
            aF[j] = *(const bf16x8*)(SAp + pswz(wr*128 + (MH)*64 + j*16 + lrow, quad)); \
        if (RB) {                                                               \
            const unsigned short* SBp = sB[BUF] + (KS) * 8192;                  \
            _Pragma("unroll")                                                   \
            for (int g = 0; g < 4; ++g)                                         \
                bF[g] = *(const bf16x8*)(SBp + pswz(wc*64 + g*16 + lrow, quad)); \
        }                                                                       \
        STG;                                                                    \
        SBAR();                                                                 \
        asm volatile("s_waitcnt lgkmcnt(0)" ::: "memory");                      \
        __builtin_amdgcn_sched_barrier(0);                                      \
        __builtin_amdgcn_s_setprio(1);                                          \
        _Pragma("unroll")                                                       \
        for (int j = 0; j < 4; ++j)                                             \
            _Pragma("unroll")                                                   \
            for (int g = 0; g < 4; ++g)                                         \
                acc[(MH)*4+j][g] = MFMA16(aF[j], bF[g], acc[(MH)*4+j][g], 0, 0, 0); \
        __builtin_amdgcn_s_setprio(0);                                          \
        VM;                                                                     \
        SBAR();                                                                 \
    }

template<bool FUSE>
__global__ __launch_bounds__(512, 2)
void gemm8p_kernel(const unsigned short* __restrict__ A0, const unsigned short* __restrict__ A1,
                   const unsigned short* __restrict__ A2,
                   const unsigned short* __restrict__ B0, const unsigned short* __restrict__ B1,
                   const unsigned short* __restrict__ B2,
                   float* __restrict__ Cout, int NTILES,
                   const float* __restrict__ bias, const float* __restrict__ resid)
{
    __shared__ unsigned short sA[2][16384];   // [buf][ks(2) x 8192 ushorts]
    __shared__ unsigned short sB[2][16384];

    const int tid  = threadIdx.x;
    const int lane = tid & 63;
    const int wid  = tid >> 6;
    const int quad = lane >> 4;
    const int lrow = lane & 15;
    const int wr = wid >> 2;          // 0..1  (m half of the 256 tile)
    const int wc = wid & 3;           // 0..3  (n quarter)

    // bijective XCD swizzle (grid % 8 == 0), then n-FASTEST decomposition:
    // the 5 n-tiles of one m-panel are adjacent in sw -> A panel L2/L3 reuse.
    const int nwg = gridDim.x;
    const int cpx = nwg >> 3;
    int sw = ((int)blockIdx.x & 7) * cpx + ((int)blockIdx.x >> 3);
    const int mt = sw / 5;
    const int m0 = mt * 256;                  // 128 m-tiles
    const int n0 = (sw - mt * 5) * 256;       // 5 n-tiles (fast)

    // staging: chunk c = tid + j*512 in [0,1024); pair-packed involution.
    // rr=c>>3, l=(c&7)^(rr&7), row=2rr+(l>>2), jj=l&3 -> 4 lanes = 64B segment.
    int voff[2], cdst[2];
    #pragma unroll
    for (int j = 0; j < 2; ++j) {
        const int c = tid + j * 512;
        const int rr = c >> 3;
        const int l  = (c & 7) ^ (rr & 7);
        const int row = 2 * rr + (l >> 2);
        const int jj  = l & 3;
        voff[j] = row * 1280 + jj * 8;
        cdst[j] = c * 8;
    }

    auto stageA = [&](int t, int ks) {
        const int seg = t / SEGT_;
        const int kt  = t - seg * SEGT_;
        const unsigned short* Ab = (seg == 0) ? A0 : (seg == 1) ? A1 : A2;
        const size_t base = (size_t)m0 * 1280 + kt * 64 + ks * 32;
        unsigned short* reg = &sA[t & 1][ks * 8192];
        #pragma unroll
        for (int j = 0; j < 2; ++j)
            __builtin_amdgcn_global_load_lds((const AS_G void*)(Ab + base + voff[j]),
                                             (AS_L void*)(reg + cdst[j]), 16, 0, 0);
    };
    auto stageB = [&](int t, int ks) {
        const int seg = t / SEGT_;
        const int kt  = t - seg * SEGT_;
        const unsigned short* Bb = (seg == 0) ? B0 : (seg == 1) ? B1 : B2;
        const size_t base = (size_t)n0 * 1280 + kt * 64 + ks * 32;
        unsigned short* reg = &sB[t & 1][ks * 8192];
        #pragma unroll
        for (int j = 0; j < 2; ++j)
            __builtin_amdgcn_global_load_lds((const AS_G void*)(Bb + base + voff[j]),
                                             (AS_L void*)(reg + cdst[j]), 16, 0, 0);
    };

    f32x4 acc[8][4] = {};
    bf16x8 aF[4], bF[4];

    const int NI = NTILES >> 1;               // iterations (2 tiles each); NI >= 2

    // prologue: tile0 all 4 units + tile1 ks0 units, then allow 4 newest units
    stageA(0, 0); stageB(0, 0); stageA(0, 1); stageB(0, 1); stageA(1, 0); stageB(1, 0);
    VM8;        // 6 units outstanding-cap 8 loads => oldest 2 units (tile0 ks0) landed
    SBAR();

    for (int it = 0; it < NI - 1; ++it) {
        const int t0 = 2 * it, t1 = 2 * it + 1;
        PHASE(0, 0, 0, true,  stageA(t1, 1),     NOP);
        PHASE(0, 0, 1, false, stageB(t1, 1),     VM8);
        PHASE(0, 1, 0, true,  stageA(t0 + 2, 0), NOP);
        PHASE(0, 1, 1, false, stageB(t0 + 2, 0), VM8);
        PHASE(1, 0, 0, true,  stageA(t0 + 2, 1), NOP);
        PHASE(1, 0, 1, false, stageB(t0 + 2, 1), VM8);
        PHASE(1, 1, 0, true,  stageA(t1 + 2, 0), NOP);
        PHASE(1, 1, 1, false, stageB(t1 + 2, 0), VM8);
    }
    {   // peeled last iteration: only t1's ks1 still to stage, then drain
        const int t1 = NTILES - 1;
        PHASE(0, 0, 0, true,  stageA(t1, 1), NOP);
        PHASE(0, 0, 1, false, stageB(t1, 1), VM0);
        PHASE(0, 1, 0, true,  NOP, NOP);
        PHASE(0, 1, 1, false, NOP, NOP);
        PHASE(1, 0, 0, true,  NOP, NOP);
        PHASE(1, 0, 1, false, NOP, NOP);
        PHASE(1, 1, 0, true,  NOP, NOP);
        PHASE(1, 1, 1, false, NOP, NOP);
    }

    // Epilogue: C/D layout col = lane&15, row = quad*4 + reg (m89/m91-verified)
    #pragma unroll
    for (int f = 0; f < 8; ++f) {
        #pragma unroll
        for (int g = 0; g < 4; ++g) {
            const int col = n0 + wc * 64 + g * 16 + lrow;
            #pragma unroll
            for (int r2 = 0; r2 < 4; ++r2) {
                const int row = m0 + wr * 128 + f * 16 + quad * 4 + r2;
                float v = acc[f][g][r2];
                if constexpr (FUSE)
                    v += bias[col] + resid[(size_t)row * 1280 + col];
                Cout[(size_t)row * 1280 + col] = v;
            }
        }
    }
}

// ---------------------------------------------------------------------------
// fp32 GEMM, 64x64 tile, BK=16, 256 threads, 4x4 micro-tile. For K/V
// projections (M=616, K=2048, N=1280) — stays fp32 (feeds scoring path).
// ---------------------------------------------------------------------------
__global__ __launch_bounds__(256)
void gemm64_kernel(const float* __restrict__ A,
                   const float* __restrict__ B0, const float* __restrict__ B1,
                   float* __restrict__ C0, float* __restrict__ C1,
                   int M, int N, int K)
{
    const float* Bm = blockIdx.z ? B1 : B0;
    float* Cout = blockIdx.z ? C1 : C0;
    __shared__ float As[16][64];
    __shared__ float Bs[16][64];
    const int tid = threadIdx.x;
    const int n0 = blockIdx.x * 64;
    const int m0 = blockIdx.y * 64;
    const int tx = tid & 15, ty = tid >> 4;
    const int ar = tid >> 2;
    const int ak = (tid & 3) << 2;
    const int bk = tid >> 4;
    const int bn = (tid & 15) << 2;

    float acc[4][4] = {};
    const int arow = m0 + ar;
    const bool avalid = arow < M;
    const float* Ap = A + (size_t)arow * K + ak;
    const float* Bp = Bm + (size_t)bk * N + n0 + bn;

    for (int k0 = 0; k0 < K; k0 += 16) {
        const float4 a = avalid ? *(const float4*)(Ap + k0) : make_float4(0.f,0.f,0.f,0.f);
        const float4 b = *(const float4*)(Bp + (size_t)k0 * N);
        __syncthreads();
        As[ak+0][ar] = a.x; As[ak+1][ar] = a.y; As[ak+2][ar] = a.z; As[ak+3][ar] = a.w;
        *(float4*)&Bs[bk][bn] = b;
        __syncthreads();
        #pragma unroll
        for (int kk = 0; kk < 16; ++kk) {
            const float4 av = *(const float4*)&As[kk][ty*4];
            const float4 bv = *(const float4*)&Bs[kk][tx*4];
            const float arr[4] = {av.x, av.y, av.z, av.w};
            const float brr[4] = {bv.x, bv.y, bv.z, bv.w};
            #pragma unroll
            for (int r = 0; r < 4; ++r)
                #pragma unroll
                for (int c = 0; c < 4; ++c)
                    acc[r][c] = fmaf(arr[r], brr[c], acc[r][c]);
        }
    }
    #pragma unroll
    for (int r = 0; r < 4; ++r) {
        const int row = m0 + ty * 4 + r;
        if (row < M) {
            const float4 cv = make_float4(acc[r][0], acc[r][1], acc[r][2], acc[r][3]);
            *(float4*)(Cout + (size_t)row * N + n0 + tx * 4) = cv;
        }
    }
}

__device__ inline bool first_pair(float va, int ia, float vb, int ib)
{
    return (va > vb) || (va == vb && ia < ib);
}

// descending by (value, then index asc) — matches lax.top_k tie-break
__device__ inline void bitonic_desc(float* vals, int* idxs, int n, int tid, int nt)
{
    for (int k = 2; k <= n; k <<= 1) {
        for (int j = k >> 1; j > 0; j >>= 1) {
            __syncthreads();
            for (int i = tid; i < n; i += nt) {
                const int l = i ^ j;
                if (l > i) {
                    const float vi = vals[i], vl = vals[l];
                    const int   ii = idxs[i], il = idxs[l];
                    const bool up = (i & k) == 0;
                    const bool sw = up ? first_pair(vl, il, vi, ii)
                                       : first_pair(vi, ii, vl, il);
                    if (sw) { vals[i] = vl; vals[l] = vi; idxs[i] = il; idxs[l] = ii; }
                }
            }
        }
    }
    __syncthreads();
}

// ---------------------------------------------------------------------------
// Pass A (MFMA): swapped QK^T -> per-lane logits for 16 s-cols (s = lane&15),
// t = nt*16 + quad*4 + r. 4-product split bf16 QK (fp32-level accuracy; the
// logits feed the top-k masks, which must not flip). Softmax over t = register
// max/sum + shfl_xor(16/32) quad reduce. Accumulate sum_s p per t -> tokp.
// Grid: 2560 blocks = b(8) x h(20) x s-chunk(16); 4 waves x 4 s-tiles = 256 s.
// ---------------------------------------------------------------------------
__global__ __launch_bounds__(256)
void pass_a_kernel(const float* __restrict__ q, const float* __restrict__ kbuf,
                   float* __restrict__ tokp)
{
    __shared__ unsigned short khi[80 * 64];   // [t][d] bf16, XOR-swizzled rows
    __shared__ unsigned short klo[80 * 64];
    __shared__ float wsum[4][80];
    const int g = blockIdx.x;
    const int b = g / 320;
    const int rem = g % 320;
    const int h = rem >> 4;
    const int chunk = rem & 15;
    const int tid = threadIdx.x;

    // stage K slice -> swizzled bf16 hi/lo (T2 swizzle: byte ^= (t&7)<<4)
    for (int i = tid; i < 80 * 16; i += 256) {
        const int t = i >> 4, j = i & 15;                 // d0 = 4*j
        float4 v = make_float4(0.f, 0.f, 0.f, 0.f);
        if (t < T_) v = *(const float4*)(kbuf + (size_t)(b * T_ + t) * HD_ + h * D_ + 4 * j);
        ushort4 hh, ll;
        hh.x = f2bf(v.x); ll.x = f2bf(v.x - bf2f(hh.x));
        hh.y = f2bf(v.y); ll.y = f2bf(v.y - bf2f(hh.y));
        hh.z = f2bf(v.z); ll.z = f2bf(v.z - bf2f(hh.z));
        hh.w = f2bf(v.w); ll.w = f2bf(v.w - bf2f(hh.w));
        const int byt = t * 128 + ((8 * j) ^ ((t & 7) << 4));
        *(ushort4*)((char*)khi + byt) = hh;
        *(ushort4*)((char*)klo + byt) = ll;
    }
    __syncthreads();

    const int wid = tid >> 6, lane = tid & 63;
    const int lrow = lane & 15, quad = lane >> 4;

    f32x4 tokacc[5] = {};
    for (int st = 0; st < 4; ++st) {
        const int s = chunk * 256 + wid * 64 + st * 16 + lrow;
        const float* qp = q + (size_t)(b * S_ + s) * HD_ + h * D_;
        bf16x8 qhi[2], qlo[2];
        #pragma unroll
        for (int ks = 0; ks < 2; ++ks)
            split_frag(qp + ks * 32 + quad * 8, qhi[ks], qlo[ks]);

        f32x4 acc[5] = {};
        #pragma unroll
        for (int nt = 0; nt < 5; ++nt) {
            #pragma unroll
            for (int ks = 0; ks < 2; ++ks) {
                const int krow = nt * 16 + lrow;
                const int byt = krow * 128 + ((64 * ks + 16 * quad) ^ ((krow & 7) << 4));
                const bf16x8 kh = *(const bf16x8*)((const char*)khi + byt);
                const bf16x8 kl = *(const bf16x8*)((const char*)klo + byt);
                acc[nt] = MFMA16(kh, qhi[ks], acc[nt], 0, 0, 0);
                acc[nt] = MFMA16(kh, qlo[ks], acc[nt], 0, 0, 0);
                acc[nt] = MFMA16(kl, qhi[ks], acc[nt], 0, 0, 0);
                acc[nt] = MFMA16(kl, qlo[ks], acc[nt], 0, 0, 0);
            }
        }
        float m = -1e30f;
        #pragma unroll
        for (int nt = 0; nt < 5; ++nt)
            #pragma unroll
            for (int r = 0; r < 4; ++r) {
                const int t = nt * 16 + quad * 4 + r;
                const float l = (t < T_) ? acc[nt][r] * SCALE_ : -1e30f;
                acc[nt][r] = l;
                m = fmaxf(m, l);
            }
        m = fmaxf(m, __shfl_xor(m, 16, 64));
        m = fmaxf(m, __shfl_xor(m, 32, 64));
        float Lp = 0.f;
        #pragma unroll
        for (int nt = 0; nt < 5; ++nt)
            #pragma unroll
            for (int r = 0; r < 4; ++r) {
                const float e = __expf(acc[nt][r] - m);
                acc[nt][r] = e;
                Lp += e;
            }
        float L = Lp + __shfl_xor(Lp, 16, 64);
        L += __shfl_xor(L, 32, 64);
        const float invL = 1.0f / L;
        #pragma unroll
        for (int nt = 0; nt < 5; ++nt)
            #pragma unroll
            for (int r = 0; r < 4; ++r)
                tokacc[nt][r] = fmaf(acc[nt][r], invL, tokacc[nt][r]);
    }
    // reduce over the 16 s-columns (lane bits 0..3), write per-wave partials
    #pragma unroll
    for (int nt = 0; nt < 5; ++nt)
        #pragma unroll
        for (int r = 0; r < 4; ++r) {
            float v = tokacc[nt][r];
            v += __shfl_xor(v, 1, 64);
            v += __shfl_xor(v, 2, 64);
            v += __shfl_xor(v, 4, 64);
            v += __shfl_xor(v, 8, 64);
            if (lrow == 0) wsum[wid][nt * 16 + quad * 4 + r] = v;
        }
    __syncthreads();
    for (int t = tid; t < T_; t += 256)
        tokp[(size_t)g * T_ + t] = (wsum[0][t] + wsum[1][t]) + (wsum[2][t] + wsum[3][t]);
}

// ---------------------------------------------------------------------------
// Top-k over 77 token scores per batch -> tok_mask. 8 blocks x 128 threads.
// ---------------------------------------------------------------------------
__global__ __launch_bounds__(128)
void topk_tok_kernel(const float* __restrict__ tokp, float* __restrict__ tokm)
{
    __shared__ float vals[128];
    __shared__ int idxs[128];
    const int b = blockIdx.x, tid = threadIdx.x;
    float v = -1e30f;
    if (tid < T_) {
        float sm = 0.f;
        for (int j = 0; j < 320; ++j) sm += tokp[(size_t)(b * 320 + j) * T_ + tid];
        v = sm;
    }
    vals[tid] = v; idxs[tid] = tid;
    bitonic_desc(vals, idxs, 128, tid, 128);
    if (tid < T_) tokm[b * T_ + tid] = 0.f;
    __syncthreads();
    if (tid < KTOK_) tokm[b * T_ + idxs[tid]] = 1.0f;
}

// ---------------------------------------------------------------------------
// K/V cross-frame mixing: kd = k2-k (delta, mask folded in), v2 = mixed v.
// ---------------------------------------------------------------------------
__global__ __launch_bounds__(256)
void mix_kernel(const float* __restrict__ kbuf, const float* __restrict__ vbuf,
                const float* __restrict__ tokm,
                float* __restrict__ kd, float* __restrict__ v2)
{
    const int i = blockIdx.x * 256 + threadIdx.x;   // < 77*1280 = 98560
    const int t = i / HD_;
    float ks = 0.f, vs = 0.f;
    #pragma unroll
    for (int b = 0; b < B_; ++b) {
        ks += kbuf[(size_t)b * T_ * HD_ + i];
        vs += vbuf[(size_t)b * T_ * HD_ + i];
    }
    #pragma unroll
    for (int b = 0; b < B_; ++b) {
        const size_t gi = (size_t)b * T_ * HD_ + i;
        const float msk = tokm[b * T_ + t];
        const float kx = kbuf[gi], vx = vbuf[gi];
        kd[gi] = CMIX_ * msk * ((ks - 8.f * kx) * (1.0f / 7.0f));
        v2[gi] = vx + CMIX_ * msk * ((vs - 8.f * vx) * (1.0f / 7.0f));
    }
}

// ---------------------------------------------------------------------------
// Fused pass B+C (MFMA): swapped QK^T gives per-lane l1 (split, 4 products)
// and l2 = l1 + q·kd (kd bf16-hi; mask folded into kd). Register softmax for
// both; posp = masked mass of softmax(l1); p2 = softmax(l2) -> LDS round-trip
// per 32-wide k-step (hi/lo) -> swapped PV mfma(V^T, P) -> ctx.
// ---------------------------------------------------------------------------
__global__ __launch_bounds__(256)
void pass_bc_kernel(const float* __restrict__ q, const float* __restrict__ kbuf,
                    const float* __restrict__ kd, const float* __restrict__ v2,
                    const float* __restrict__ tokm,
                    float* __restrict__ posp, float* __restrict__ ctx)
{
    __shared__ unsigned short khi[80 * 64];     // [t][d] XOR-swizzled
    __shared__ unsigned short klo[80 * 64];
    __shared__ unsigned short kdh[80 * 64];
    __shared__ unsigned short vThi[64 * 88];    // [d][t] rows padded to 88
    __shared__ unsigned short vTlo[64 * 88];
    __shared__ unsigned short vguard[128];      // zeroed guard for vT overreads
    __shared__ unsigned short Pbuf[4][2][16 * 40]; // per-wave [hi/lo][s][tloc]
    __shared__ float smaskf[80];

    const int g = blockIdx.x;
    const int b = g / 320;
    const int rem = g % 320;
    const int h = rem >> 4;
    const int chunk = rem & 15;
    const int tid = threadIdx.x;

    // ---- stage K (hi/lo) + Kd (hi), swizzled ----
    for (int i = tid; i < 80 * 16; i += 256) {
        const int t = i >> 4, j = i & 15;
        float4 vk = make_float4(0.f, 0.f, 0.f, 0.f);
        float4 vd = make_float4(0.f, 0.f, 0.f, 0.f);
        if (t < T_) {
            const size_t gi = (size_t)(b * T_ + t) * HD_ + h * D_ + 4 * j;
            vk = *(const float4*)(kbuf + gi);
            vd = *(const float4*)(kd + gi);
        }
        ushort4 hh, ll, dd;
        hh.x = f2bf(vk.x); ll.x = f2bf(vk.x - bf2f(hh.x)); dd.x = f2bf(vd.x);
        hh.y = f2bf(vk.y); ll.y = f2bf(vk.y - bf2f(hh.y)); dd.y = f2bf(vd.y);
        hh.z = f2bf(vk.z); ll.z = f2bf(vk.z - bf2f(hh.z)); dd.z = f2bf(vd.z);
        hh.w = f2bf(vk.w); ll.w = f2bf(vk.w - bf2f(hh.w)); dd.w = f2bf(vd.w);
        const int byt = t * 128 + ((8 * j) ^ ((t & 7) << 4));
        *(ushort4*)((char*)khi + byt) = hh;
        *(ushort4*)((char*)klo + byt) = ll;
        *(ushort4*)((char*)kdh + byt) = dd;
    }
    // ---- stage V^T (hi/lo): rows d (88 cols, zero-padded past t=76) ----
    for (int i = tid; i < 64 * 22; i += 256) {
        const int d = i / 22, jg = i - d * 22;           // cols t = 4*jg..+3
        float vv[4];
        #pragma unroll
        for (int r = 0; r < 4; ++r) {
            const int t = 4 * jg + r;
            vv[r] = (t < T_) ? v2[(size_t)(b * T_ + t) * HD_ + h * D_ + d] : 0.f;
        }
        ushort4 hh, ll;
        hh.x = f2bf(vv[0]); ll.x = f2bf(vv[0] - bf2f(hh.x));
        hh.y = f2bf(vv[1]); ll.y = f2bf(vv[1] - bf2f(hh.y));
        hh.z = f2bf(vv[2]); ll.z = f2bf(vv[2] - bf2f(hh.z));
        hh.w = f2bf(vv[3]); ll.w = f2bf(vv[3] - bf2f(hh.w));
        const int byt = d * 176 + 8 * jg;
        *(ushort4*)((char*)vThi + byt) = hh;
        *(ushort4*)((char*)vTlo + byt) = ll;
    }
    for (int t = tid; t < 80; t += 256) smaskf[t] = (t < T_) ? tokm[b * T_ + t] : 0.f;
    for (int i = tid; i < 128; i += 256) vguard[i] = 0;
    __syncthreads();

    const int wid = tid >> 6, lane = tid & 63;
    const int lrow = lane & 15, quad = lane >> 4;
    unsigned short* Ph = &Pbuf[wid][0][0];
    unsigned short* Pl = &Pbuf[wid][1][0];

    // hoist per-lane token-mask values (constant across s-tiles)
    float smv[5][4];
    #pragma unroll
    for (int nt = 0; nt < 5; ++nt)
        #pragma unroll
        for (int r = 0; r < 4; ++r)
            smv[nt][r] = smaskf[nt * 16 + quad * 4 + r];

    for (int st = 0; st < 4; ++st) {
        const int s = chunk * 256 + wid * 64 + st * 16 + lrow;
        const float* qp = q + (size_t)(b * S_ + s) * HD_ + h * D_;
        bf16x8 qhi[2], qlo[2];
        #pragma unroll
        for (int ks = 0; ks < 2; ++ks)
            split_frag(qp + ks * 32 + quad * 8, qhi[ks], qlo[ks]);

        f32x4 acc1[5] = {}, accd[5] = {};
        #pragma unroll
        for (int nt = 0; nt < 5; ++nt) {
            #pragma unroll
            for (int ks = 0; ks < 2; ++ks) {
                const int krow = nt * 16 + lrow;
                const int byt = krow * 128 + ((64 * ks + 16 * quad) ^ ((krow & 7) << 4));
                const bf16x8 kh = *(const bf16x8*)((const char*)khi + byt);
                const bf16x8 kl = *(const bf16x8*)((const char*)klo + byt);
                const bf16x8 kdv = *(const bf16x8*)((const char*)kdh + byt);
                acc1[nt] = MFMA16(kh, qhi[ks], acc1[nt], 0, 0, 0);
                acc1[nt] = MFMA16(kh, qlo[ks], acc1[nt], 0, 0, 0);
                acc1[nt] = MFMA16(kl, qhi[ks], acc1[nt], 0, 0, 0);
                acc1[nt] = MFMA16(kl, qlo[ks], acc1[nt], 0, 0, 0);
                accd[nt] = MFMA16(kdv, qhi[ks], accd[nt], 0, 0, 0);
            }
        }

        // logits + dual softmax (l1: pos score; l2: second attention)
        float m1 = -1e30f, m2 = -1e30f;
        f32x4 l2v[5];
        #pragma unroll
        for (int nt = 0; nt < 5; ++nt)
            #pragma unroll
            for (int r = 0; r < 4; ++r) {
                const int t = nt * 16 + quad * 4 + r;
                const bool valid = t < T_;
                const float l1 = valid ? acc1[nt][r] * SCALE_ : -1e30f;
                const float l2 = valid ? l1 + accd[nt][r] * SCALE_ : -1e30f;
                acc1[nt][r] = l1;
                l2v[nt][r] = l2;
                m1 = fmaxf(m1, l1);
                m2 = fmaxf(m2, l2);
            }
        m1 = fmaxf(m1, __shfl_xor(m1, 16, 64));
        m1 = fmaxf(m1, __shfl_xor(m1, 32, 64));
        m2 = fmaxf(m2, __shfl_xor(m2, 16, 64));
        m2 = fmaxf(m2, __shfl_xor(m2, 32, 64));
        float L1p = 0.f, Smp = 0.f, L2p = 0.f;
        #pragma unroll
        for (int nt = 0; nt < 5; ++nt)
            #pragma unroll
            for (int r = 0; r < 4; ++r) {
                const float e1 = __expf(acc1[nt][r] - m1);
                L1p += e1;
                Smp = fmaf(e1, smv[nt][r], Smp);
                const float e2 = __expf(l2v[nt][r] - m2);
                l2v[nt][r] = e2;
                L2p += e2;
            }
        float L1 = L1p + __shfl_xor(L1p, 16, 64); L1 += __shfl_xor(L1, 32, 64);
        float Sm = Smp + __shfl_xor(Smp, 16, 64); Sm += __shfl_xor(Sm, 32, 64);
        float L2 = L2p + __shfl_xor(L2p, 16, 64); L2 += __shfl_xor(L2, 32, 64);
        if (quad == 0) posp[(size_t)(b * H_ + h) * S_ + s] = Sm / L1;
        const float invL2 = 1.0f / L2;
        #pragma unroll
        for (int nt = 0; nt < 5; ++nt)
            #pragma unroll
            for (int r = 0; r < 4; ++r)
                l2v[nt][r] *= invL2;

        // PV: per 32-wide k-step, P -> LDS (hi/lo) -> B-frags, V^T A-frags
        f32x4 pv[4] = {};
        #pragma unroll
        for (int ks = 0; ks < 3; ++ks) {
            asm volatile("s_waitcnt lgkmcnt(0)" ::: "memory");
            __builtin_amdgcn_sched_barrier(0);
            #pragma unroll
            for (int half = 0; half < 2; ++half) {
                const int nt = 2 * ks + half;
                ushort4 ph = {0, 0, 0, 0}, plw = {0, 0, 0, 0};
                if (nt < 5) {
                    ph.x = f2bf(l2v[nt][0]); plw.x = f2bf(l2v[nt][0] - bf2f(ph.x));
                    ph.y = f2bf(l2v[nt][1]); plw.y = f2bf(l2v[nt][1] - bf2f(ph.y));
                    ph.z = f2bf(l2v[nt][2]); plw.z = f2bf(l2v[nt][2] - bf2f(ph.z));
                    ph.w = f2bf(l2v[nt][3]); plw.w = f2bf(l2v[nt][3] - bf2f(ph.w));
                }
                const int pb = lrow * 80 + 32 * half + 8 * quad;
                *(ushort4*)((char*)Ph + pb) = ph;
                *(ushort4*)((char*)Pl + pb) = plw;
            }
            asm volatile("s_waitcnt lgkmcnt(0)" ::: "memory");
            __builtin_amdgcn_sched_barrier(0);
            const bf16x8 pH = *(const bf16x8*)((const char*)Ph + lrow * 80 + quad * 16);
            const bf16x8 pL = *(const bf16x8*)((const char*)Pl + lrow * 80 + quad * 16);
            #pragma unroll
            for (int mt = 0; mt < 4; ++mt) {
                const int vb = (mt * 16 + lrow) * 176 + 64 * ks + 16 * quad;
                const bf16x8 vH = *(const bf16x8*)((const char*)vThi + vb);
                const bf16x8 vL = *(const bf16x8*)((const char*)vTlo + vb);
                pv[mt] = MFMA16(vH, pH, pv[mt], 0, 0, 0);
                pv[mt] = MFMA16(vH, pL, pv[mt], 0, 0, 0);
                pv[mt] = MFMA16(vL, pH, pv[mt], 0, 0, 0);
            }
        }
        // ctx write: col = lane&15 = s, row(d) = mt*16 + quad*4 + reg
        float* cp = ctx + (size_t)(b * S_ + s) * HD_ + h * D_;
        #pragma unroll
        for (int mt = 0; mt < 4; ++mt) {
            const float4 o = make_float4(pv[mt][0], pv[mt][1], pv[mt][2], pv[mt][3]);
            *(float4*)(cp + mt * 16 + quad * 4) = o;
        }
    }
}

// ---------------------------------------------------------------------------
// Top-k over 4096 position scores per batch -> pos_mask. 8 blocks x 1024.
// ---------------------------------------------------------------------------
__global__ __launch_bounds__(1024)
void topk_pos_kernel(const float* __restrict__ posp, float* __restrict__ posm)
{
    __shared__ float vals[S_];
    __shared__ int idxs[S_];
    const int b = blockIdx.x, tid = threadIdx.x;
    for (int s = tid; s < S_; s += 1024) {
        float sm = 0.f;
        for (int h = 0; h < H_; ++h) sm += posp[(size_t)(b * H_ + h) * S_ + s];
        vals[s] = sm; idxs[s] = s;
    }
    bitonic_desc(vals, idxs, S_, tid, 1024);
    for (int s = tid; s < S_; s += 1024) posm[b * S_ + s] = 0.f;
    __syncthreads();
    for (int i = tid; i < KPOS_; i += 1024) posm[b * S_ + idxs[i]] = 1.0f;
}

// ---------------------------------------------------------------------------
// Batch-sum of context over b: csum[s,hd] = sum_b ctx[b,s,hd]. float4 lanes.
// ---------------------------------------------------------------------------
__global__ __launch_bounds__(256)
void ctxsum_kernel(const float* __restrict__ ctx, float* __restrict__ csum)
{
    const size_t i = (size_t)blockIdx.x * 256 + threadIdx.x;  // float4 index
    const float4* c = (const float4*)ctx;
    float4 a = c[i];
    #pragma unroll
    for (int b = 1; b < B_; ++b) {
        const float4 x = c[(size_t)b * (S_ * HD_ / 4) + i];
        a.x += x.x; a.y += x.y; a.z += x.z; a.w += x.w;
    }
    ((float4*)csum)[i] = a;
}

// ---------------------------------------------------------------------------
extern "C" void kernel_launch(void* const* d_in, const int* in_sizes, int n_in,
                              void* d_out, int out_size, void* d_ws, size_t ws_size,
                              hipStream_t stream)
{
    const float* hidden = (const float*)d_in[0];
    const float* enc    = (const float*)d_in[1];
    const float* Wq     = (const float*)d_in[2];
    const float* Wk     = (const float*)d_in[3];
    const float* Wv     = (const float*)d_in[4];
    const float* Wo     = (const float*)d_in[5];
    const float* bo     = (const float*)d_in[6];
    float* out = (float*)d_out;

    char* w = (char*)d_ws;
    float* q    = (float*)w; w += (size_t)M1_ * HD_ * 4;
    float* ctx  = (float*)w; w += (size_t)M1_ * HD_ * 4;
    float* kbuf = (float*)w; w += (size_t)B_ * T_ * HD_ * 4;
    float* vbuf = (float*)w; w += (size_t)B_ * T_ * HD_ * 4;
    float* kd   = (float*)w; w += (size_t)B_ * T_ * HD_ * 4;
    float* v2   = (float*)w; w += (size_t)B_ * T_ * HD_ * 4;
    float* csum = (float*)w; w += (size_t)S_ * HD_ * 4;
    float* tokp = (float*)w; w += (size_t)2560 * T_ * 4;
    float* posp = (float*)w; w += (size_t)B_ * H_ * S_ * 4;
    float* tokm = (float*)w; w += (size_t)B_ * T_ * 4;
    float* posm = (float*)w; w += (size_t)B_ * S_ * 4;
    unsigned short* Ahi   = (unsigned short*)w; w += (size_t)M1_ * HD_ * 2;
    unsigned short* Alo   = (unsigned short*)w; w += (size_t)M1_ * HD_ * 2;
    unsigned short* ctxb  = (unsigned short*)w; w += (size_t)M1_ * HD_ * 2;
    unsigned short* WqhiT = (unsigned short*)w; w += (size_t)C_ * HD_ * 2;
    unsigned short* WqloT = (unsigned short*)w; w += (size_t)C_ * HD_ * 2;
    unsigned short* WohiT = (unsigned short*)w; w += (size_t)HD_ * C_ * 2;
    unsigned short* WoloT = (unsigned short*)w; w += (size_t)HD_ * C_ * 2;
    (void)ws_size; (void)in_sizes; (void)n_in; (void)out_size;

    // 1. Split hidden -> bf16 hi/lo; weights -> transposed bf16 hi/lo
    split_convert_kernel<<<M1_ * HD_ / 4 / 256, 256, 0, stream>>>(hidden, Ahi, Alo);
    wsplitT_kernel<<<dim3(40, 40), 256, 0, stream>>>(Wq, WqhiT, WqloT);
    wsplitT_kernel<<<dim3(40, 40), 256, 0, stream>>>(Wo, WohiT, WoloT);
    // 2. Q projection: 8-phase 256^2 GEMM; split-bf16 via 3-segment K concat
    //    (Ah*Bh + Ah*Bl + Al*Bh), NTILES = 60. n-fastest block order (r5).
    gemm8p_kernel<false><<<640, 512, 0, stream>>>(
        Ahi, Ahi, Alo, WqhiT, WqloT, WqhiT, q, 60, nullptr, nullptr);
    // 3. K and V projections (fp32 — feeds scoring path)
    gemm64_kernel<<<dim3(20, 10, 2), 256, 0, stream>>>(
        enc, Wk, Wv, kbuf, vbuf, MKV_, HD_, CENC_);
    // 4. First attention (MFMA) -> token-score partials
    pass_a_kernel<<<2560, 256, 0, stream>>>(q, kbuf, tokp);
    // 5. Token top-k mask
    topk_tok_kernel<<<8, 128, 0, stream>>>(tokp, tokm);
    // 6. Cross-frame K/V mixing
    mix_kernel<<<385, 256, 0, stream>>>(kbuf, vbuf, tokm, kd, v2);
    // 7. Fused pass B (pos scores) + pass C (second attention, MFMA)
    pass_bc_kernel<<<2560, 256, 0, stream>>>(q, kbuf, kd, v2, tokm, posp, ctx);
    // 8. Position top-k mask
    topk_pos_kernel<<<8, 1024, 0, stream>>>(posp, posm);
    // 9. Batch-sum of context for mean-of-others injection
    ctxsum_kernel<<<S_ * HD_ / 4 / 256, 256, 0, stream>>>(ctx, csum);
    // 10. Injection + bf16 convert of context (A operand of O-proj)
    inject_convert_kernel<<<M1_ * HD_ / 4 / 256, 256, 0, stream>>>(ctx, csum, posm, ctxb);
    // 11. O projection: 8-phase GEMM, single segment (NTILES=20), fused
    //     bias + residual epilogue. n-fastest block order (r5).
    gemm8p_kernel<true><<<640, 512, 0, stream>>>(
        ctxb, ctxb, ctxb, WohiT, WohiT, WohiT, out, 20, bo, hidden);
}